// Round 2
// 7464.410 us; speedup vs baseline: 1.1023x; 1.1023x over previous
//
#include <hip/hip_runtime.h>
#include <cmath>

// Problem constants (fixed by the reference file)
#define B_ 1024
#define F_ 4096
#define V_ 20000
#define E_ 512
#define H_ 1024
#define L_ 20
#define D_ 4

typedef __bf16 bf16x8 __attribute__((ext_vector_type(8)));
typedef float  f32x4  __attribute__((ext_vector_type(4)));

#define BM 128
#define BN 128
#define BK 32

// padded row count for probs planes so loads need no guard (157*128)
#define VPAD 20096

// ---------------------------------------------------------------------------
// async global->LDS, 16B per lane. LDS dest is wave-uniform base + lane*16:
// our linear [rows][32]bf16 layout with thread t -> byte t*16 satisfies that.
// ---------------------------------------------------------------------------
__device__ __forceinline__ void gld_lds16(const void* g, void* l)
{
    __builtin_amdgcn_global_load_lds(
        (const __attribute__((address_space(1))) void*)g,
        (__attribute__((address_space(3))) void*)l, 16, 0, 0);
}

// ---------------------------------------------------------------------------
// OLD proven kernel: fp32 inputs, in-staging bf16 hi/lo split, 3 MFMAs/chunk.
// Kept for one-shot GEMMs (h0, aff_r, score mats) and the ws_size fallback.
// ---------------------------------------------------------------------------
__global__ __launch_bounds__(256, 2) void gemm_nt_split(
    const float* __restrict__ A1, const float* __restrict__ W1, int K1,
    const float* __restrict__ A2, const float* __restrict__ W2, int K2,
    const float* __restrict__ b1, const float* __restrict__ b2,
    float* __restrict__ C, int M, int N)
{
    __shared__ __align__(16) __bf16 As_hi[BM][BK];
    __shared__ __align__(16) __bf16 As_lo[BM][BK];
    __shared__ __align__(16) __bf16 Ws_hi[BN][BK];
    __shared__ __align__(16) __bf16 Ws_lo[BN][BK];

    const int tid  = threadIdx.x;
    const int bm   = blockIdx.y * BM;
    const int bn   = blockIdx.x * BN;
    const int srow = tid >> 1;
    const int scol = (tid & 1) * 16;
    const int lane = tid & 63;
    const int wv   = tid >> 6;
    const int wm   = (wv & 1) * 64;
    const int wn   = (wv >> 1) * 64;
    const int fm   = lane & 15;
    const int fq   = lane >> 4;

    const bool wok = (bn + srow) < N;

    f32x4 acc[4][4];
#pragma unroll
    for (int i = 0; i < 4; ++i)
#pragma unroll
        for (int j = 0; j < 4; ++j) acc[i][j] = (f32x4){0.f, 0.f, 0.f, 0.f};

#pragma unroll 1
    for (int s = 0; s < 2; ++s) {
        const float* A = s ? A2 : A1;
        const float* W = s ? W2 : W1;
        const int    K = s ? K2 : K1;
        if (!A) continue;
        const float* Arow = A + (size_t)(bm + srow) * K;
        const float* Wrow = W + (size_t)(bn + srow) * K;

        for (int k0 = 0; k0 < K; k0 += BK) {
            float av[16], wvv[16];
            const float* ap = Arow + k0 + scol;
            *(float4*)&av[0]   = *(const float4*)(ap + 0);
            *(float4*)&av[4]   = *(const float4*)(ap + 4);
            *(float4*)&av[8]   = *(const float4*)(ap + 8);
            *(float4*)&av[12]  = *(const float4*)(ap + 12);
            if (wok) {
                const float* wp = Wrow + k0 + scol;
                *(float4*)&wvv[0]  = *(const float4*)(wp + 0);
                *(float4*)&wvv[4]  = *(const float4*)(wp + 4);
                *(float4*)&wvv[8]  = *(const float4*)(wp + 8);
                *(float4*)&wvv[12] = *(const float4*)(wp + 12);
            } else {
#pragma unroll
                for (int v = 0; v < 16; ++v) wvv[v] = 0.f;
            }
            __syncthreads();

#pragma unroll
            for (int u = 0; u < 16; u += 8) {
                bf16x8 hh, ll;
#pragma unroll
                for (int v = 0; v < 8; ++v) {
                    float x = av[u + v];
                    __bf16 h = (__bf16)x;
                    hh[v] = h;
                    ll[v] = (__bf16)(x - (float)h);
                }
                *(bf16x8*)&As_hi[srow][scol + u] = hh;
                *(bf16x8*)&As_lo[srow][scol + u] = ll;
            }
#pragma unroll
            for (int u = 0; u < 16; u += 8) {
                bf16x8 hh, ll;
#pragma unroll
                for (int v = 0; v < 8; ++v) {
                    float x = wvv[u + v];
                    __bf16 h = (__bf16)x;
                    hh[v] = h;
                    ll[v] = (__bf16)(x - (float)h);
                }
                *(bf16x8*)&Ws_hi[srow][scol + u] = hh;
                *(bf16x8*)&Ws_lo[srow][scol + u] = ll;
            }
            __syncthreads();

            bf16x8 ah[4], al[4];
#pragma unroll
            for (int i = 0; i < 4; ++i) {
                ah[i] = *(const bf16x8*)&As_hi[wm + i * 16 + fm][fq * 8];
                al[i] = *(const bf16x8*)&As_lo[wm + i * 16 + fm][fq * 8];
            }
#pragma unroll
            for (int j = 0; j < 4; ++j) {
                bf16x8 bh = *(const bf16x8*)&Ws_hi[wn + j * 16 + fm][fq * 8];
                bf16x8 bl = *(const bf16x8*)&Ws_lo[wn + j * 16 + fm][fq * 8];
#pragma unroll
                for (int i = 0; i < 4; ++i) {
                    acc[i][j] = __builtin_amdgcn_mfma_f32_16x16x32_bf16(
                        al[i], bh, acc[i][j], 0, 0, 0);
                    acc[i][j] = __builtin_amdgcn_mfma_f32_16x16x32_bf16(
                        ah[i], bl, acc[i][j], 0, 0, 0);
                    acc[i][j] = __builtin_amdgcn_mfma_f32_16x16x32_bf16(
                        ah[i], bh, acc[i][j], 0, 0, 0);
                }
            }
        }
    }

#pragma unroll
    for (int j = 0; j < 4; ++j) {
        int col = bn + wn + j * 16 + fm;
        if (col >= N) continue;
        float badd = (b1 ? b1[col] : 0.f) + (b2 ? b2[col] : 0.f);
#pragma unroll
        for (int i = 0; i < 4; ++i) {
            int row0 = bm + wm + i * 16 + fq * 4;
            f32x4 v = acc[i][j];
#pragma unroll
            for (int r = 0; r < 4; ++r)
                C[(size_t)(row0 + r) * N + col] = v[r] + badd;
        }
    }
}

// ---------------------------------------------------------------------------
// NEW: plane GEMM. A/W pre-split into persistent bf16 hi/lo planes.
// global_load_lds staging (no VALU conversion, no reg round-trip, half bytes).
// W planes must be row-padded to a multiple of 128 (no load guard needed;
// garbage in pad rows only reaches store-guarded C columns).
// Same 3-MFMA split math and chunk order as gemm_nt_split -> identical bits.
// ---------------------------------------------------------------------------
__global__ __launch_bounds__(256, 3) void gemm_nt_planes(
    const __bf16* __restrict__ Ah1, const __bf16* __restrict__ Al1,
    const __bf16* __restrict__ Wh1, const __bf16* __restrict__ Wl1, int K1,
    const __bf16* __restrict__ Ah2, const __bf16* __restrict__ Al2,
    const __bf16* __restrict__ Wh2, const __bf16* __restrict__ Wl2, int K2,
    const float* __restrict__ b1, const float* __restrict__ b2,
    float* __restrict__ C, int M, int N)
{
    __shared__ __align__(16) __bf16 As_hi[BM][BK];
    __shared__ __align__(16) __bf16 As_lo[BM][BK];
    __shared__ __align__(16) __bf16 Ws_hi[BN][BK];
    __shared__ __align__(16) __bf16 Ws_lo[BN][BK];

    const int tid  = threadIdx.x;
    const int bm   = blockIdx.y * BM;
    const int bn   = blockIdx.x * BN;
    // staging: thread t -> row t>>2 (0..63, +64 on 2nd issue), 8-elem col slot
    // LDS byte offset = tid*16 (wave-uniform base + lane*16 -> legal for
    // global_load_lds direct staging)
    const int srow = tid >> 2;
    const int scol = (tid & 3) * 8;
    const int lane = tid & 63;
    const int wv   = tid >> 6;
    const int wm   = (wv & 1) * 64;
    const int wn   = (wv >> 1) * 64;
    const int fm   = lane & 15;
    const int fq   = lane >> 4;

    f32x4 acc[4][4];
#pragma unroll
    for (int i = 0; i < 4; ++i)
#pragma unroll
        for (int j = 0; j < 4; ++j) acc[i][j] = (f32x4){0.f, 0.f, 0.f, 0.f};

#pragma unroll 1
    for (int s = 0; s < 2; ++s) {
        const __bf16* Ah = s ? Ah2 : Ah1;
        const __bf16* Al = s ? Al2 : Al1;
        const __bf16* Wh = s ? Wh2 : Wh1;
        const __bf16* Wl = s ? Wl2 : Wl1;
        const int     K  = s ? K2  : K1;
        if (!Ah) continue;
        const size_t aoff  = (size_t)(bm + srow) * K + scol;
        const size_t woff  = (size_t)(bn + srow) * K + scol;
        const size_t step  = (size_t)64 * K;

        for (int k0 = 0; k0 < K; k0 += BK) {
            __syncthreads();   // all waves done reading previous chunk
            gld_lds16(Ah + aoff + k0,        &As_hi[srow][scol]);
            gld_lds16(Ah + aoff + k0 + step, &As_hi[srow + 64][scol]);
            gld_lds16(Al + aoff + k0,        &As_lo[srow][scol]);
            gld_lds16(Al + aoff + k0 + step, &As_lo[srow + 64][scol]);
            gld_lds16(Wh + woff + k0,        &Ws_hi[srow][scol]);
            gld_lds16(Wh + woff + k0 + step, &Ws_hi[srow + 64][scol]);
            gld_lds16(Wl + woff + k0,        &Ws_lo[srow][scol]);
            gld_lds16(Wl + woff + k0 + step, &Ws_lo[srow + 64][scol]);
            __syncthreads();   // compiler drains vmcnt(0) before s_barrier

            bf16x8 ah[4], al[4];
#pragma unroll
            for (int i = 0; i < 4; ++i) {
                ah[i] = *(const bf16x8*)&As_hi[wm + i * 16 + fm][fq * 8];
                al[i] = *(const bf16x8*)&As_lo[wm + i * 16 + fm][fq * 8];
            }
#pragma unroll
            for (int j = 0; j < 4; ++j) {
                bf16x8 bh = *(const bf16x8*)&Ws_hi[wn + j * 16 + fm][fq * 8];
                bf16x8 bl = *(const bf16x8*)&Ws_lo[wn + j * 16 + fm][fq * 8];
#pragma unroll
                for (int i = 0; i < 4; ++i) {
                    acc[i][j] = __builtin_amdgcn_mfma_f32_16x16x32_bf16(
                        al[i], bh, acc[i][j], 0, 0, 0);
                    acc[i][j] = __builtin_amdgcn_mfma_f32_16x16x32_bf16(
                        ah[i], bl, acc[i][j], 0, 0, 0);
                    acc[i][j] = __builtin_amdgcn_mfma_f32_16x16x32_bf16(
                        ah[i], bh, acc[i][j], 0, 0, 0);
                }
            }
        }
    }

#pragma unroll
    for (int j = 0; j < 4; ++j) {
        int col = bn + wn + j * 16 + fm;
        if (col >= N) continue;
        float badd = (b1 ? b1[col] : 0.f) + (b2 ? b2[col] : 0.f);
#pragma unroll
        for (int i = 0; i < 4; ++i) {
            int row0 = bm + wm + i * 16 + fq * 4;
            f32x4 v = acc[i][j];
#pragma unroll
            for (int r = 0; r < 4; ++r)
                C[(size_t)(row0 + r) * N + col] = v[r] + badd;
        }
    }
}

// ---------------------------------------------------------------------------
// fp32 -> bf16 hi/lo plane split, 8 elems/thread
// ---------------------------------------------------------------------------
__global__ __launch_bounds__(256) void split_planes(
    const float* __restrict__ src, __bf16* __restrict__ hi,
    __bf16* __restrict__ lo, long n8)
{
    long i = (long)blockIdx.x * 256 + threadIdx.x;
    if (i >= n8) return;
    float4 a = ((const float4*)src)[2 * i];
    float4 b = ((const float4*)src)[2 * i + 1];
    float v[8] = {a.x, a.y, a.z, a.w, b.x, b.y, b.z, b.w};
    bf16x8 hh, ll;
#pragma unroll
    for (int j = 0; j < 8; ++j) {
        float x = v[j];
        __bf16 h = (__bf16)x;
        hh[j] = h;
        ll[j] = (__bf16)(x - (float)h);
    }
    ((bf16x8*)hi)[i] = hh;
    ((bf16x8*)lo)[i] = ll;
}

// ---------------------------------------------------------------------------
// LSTM pointwise; optionally emits h as bf16 hi/lo planes (free conversion)
// ---------------------------------------------------------------------------
__global__ __launch_bounds__(256) void lstm_pointwise(
    const float* __restrict__ gates, float* __restrict__ c, float* __restrict__ h,
    __bf16* __restrict__ hhi, __bf16* __restrict__ hlo)
{
    int i = blockIdx.x * blockDim.x + threadIdx.x;
    if (i >= B_ * H_) return;
    int b = i / H_, k = i % H_;
    const float* g = gates + (size_t)b * 4 * H_;
    float gi = g[k], gf = g[H_ + k], gg = g[2 * H_ + k], go = g[3 * H_ + k];
    float si = 1.f / (1.f + expf(-gi));
    float sf = 1.f / (1.f + expf(-gf));
    float so = 1.f / (1.f + expf(-go));
    float cn = sf * c[i] + si * tanhf(gg);
    c[i] = cn;
    float hv = so * tanhf(cn);
    h[i] = hv;
    if (hhi) {
        __bf16 hh = (__bf16)hv;
        hhi[i] = hh;
        hlo[i] = (__bf16)(hv - (float)hh);
    }
}

// ---------------------------------------------------------------------------
// Per-row argmax (first-occurrence) + online logsumexp
// ---------------------------------------------------------------------------
__global__ __launch_bounds__(256) void row_argmax_lse(
    const float* __restrict__ logits, int* __restrict__ tok,
    float* __restrict__ lp, int need_lp)
{
    int b = blockIdx.x;
    const float* row = logits + (size_t)b * V_;
    int tid = threadIdx.x;
    float m = -INFINITY; int mi = 0;
    float lm = -INFINITY, ls = 0.f;
    for (int j = tid; j < V_; j += 256) {
        float v = row[j];
        if (v > m) { m = v; mi = j; }
        if (need_lp) {
            if (v > lm) { ls = ls * expf(lm - v) + 1.f; lm = v; }
            else ls += expf(v - lm);
        }
    }
    __shared__ float sm[256]; __shared__ int si[256];
    __shared__ float slm[256], sls[256];
    sm[tid] = m; si[tid] = mi; slm[tid] = lm; sls[tid] = ls;
    __syncthreads();
    for (int s = 128; s > 0; s >>= 1) {
        if (tid < s) {
            float vm = sm[tid + s]; int vi = si[tid + s];
            if (vm > sm[tid] || (vm == sm[tid] && vi < si[tid])) {
                sm[tid] = vm; si[tid] = vi;
            }
            if (need_lp) {
                float am = slm[tid], as = sls[tid];
                float bm2 = slm[tid + s], bs = sls[tid + s];
                if (am >= bm2) {
                    sls[tid] = as + bs * expf(bm2 - am);
                } else {
                    sls[tid] = bs + as * expf(am - bm2);
                    slm[tid] = bm2;
                }
            }
        }
        __syncthreads();
    }
    if (tid == 0) {
        tok[b] = si[0];
        if (need_lp) lp[b] = sm[0] - (slm[0] + logf(sls[0]));
    }
}

// ---------------------------------------------------------------------------
// Embedding gathers (fp32 versions for fallback; plane versions for fast path)
// ---------------------------------------------------------------------------
__global__ __launch_bounds__(128) void gather_emb(
    const float* __restrict__ emb, const int* __restrict__ tok,
    float* __restrict__ out)
{
    int b = blockIdx.x;
    int t = tok[b];
    const float4* src = (const float4*)(emb + (size_t)t * E_);
    float4* dst = (float4*)(out + (size_t)b * E_);
    for (int e = threadIdx.x; e < E_ / 4; e += blockDim.x) dst[e] = src[e];
}

__global__ __launch_bounds__(128) void broadcast_emb(
    const float* __restrict__ emb, const int* __restrict__ sidx,
    float* __restrict__ out)
{
    int b = blockIdx.x;
    int t = sidx[0];
    const float4* src = (const float4*)(emb + (size_t)t * E_);
    float4* dst = (float4*)(out + (size_t)b * E_);
    for (int e = threadIdx.x; e < E_ / 4; e += blockDim.x) dst[e] = src[e];
}

__device__ __forceinline__ void emb_row_split(
    const float* __restrict__ emb, int t, int b, int i,
    __bf16* __restrict__ whi, __bf16* __restrict__ wlo)
{
    const float4* src = (const float4*)(emb + (size_t)t * E_);
    float4 a = src[2 * i], c2 = src[2 * i + 1];
    float v[8] = {a.x, a.y, a.z, a.w, c2.x, c2.y, c2.z, c2.w};
    bf16x8 hh, ll;
#pragma unroll
    for (int j = 0; j < 8; ++j) {
        float x = v[j];
        __bf16 h = (__bf16)x;
        hh[j] = h;
        ll[j] = (__bf16)(x - (float)h);
    }
    ((bf16x8*)(whi + (size_t)b * E_))[i] = hh;
    ((bf16x8*)(wlo + (size_t)b * E_))[i] = ll;
}

__global__ __launch_bounds__(64) void gather_emb_planes(
    const float* __restrict__ emb, const int* __restrict__ tok,
    __bf16* __restrict__ whi, __bf16* __restrict__ wlo)
{
    emb_row_split(emb, tok[blockIdx.x], blockIdx.x, threadIdx.x, whi, wlo);
}

__global__ __launch_bounds__(64) void broadcast_emb_planes(
    const float* __restrict__ emb, const int* __restrict__ sidx,
    __bf16* __restrict__ whi, __bf16* __restrict__ wlo)
{
    emb_row_split(emb, sidx[0], blockIdx.x, threadIdx.x, whi, wlo);
}

__global__ __launch_bounds__(256) void zero_f32(float* __restrict__ p, int n)
{
    int i = blockIdx.x * blockDim.x + threadIdx.x;
    if (i < n) p[i] = 0.f;
}

// ---------------------------------------------------------------------------
// Loss rows + finalize (unchanged)
// ---------------------------------------------------------------------------
__global__ __launch_bounds__(256) void loss_rows(
    const float* __restrict__ sc, const float* __restrict__ lp,
    float* __restrict__ loss_part, float* __restrict__ acc_flag)
{
    int i = blockIdx.x; int tid = threadIdx.x;
    const float* tsrow = sc + (size_t)i * B_;
    float lsum = 0.f, tps = 0.f;
    float dps[4] = {0.f, 0.f, 0.f, 0.f};
    for (int j = tid; j < B_; j += 256) {
        float tsv = tsrow[j];
        float hv = 0.f;
#pragma unroll
        for (int d = 0; d < 4; ++d) {
            float dv = sc[((size_t)(1 + d) * B_ + i) * B_ + j];
            float t = 1.f - tsv + dv;
            hv += (t > 0.f) ? t : 0.f;
            dps[d] += expf(dv);
        }
        lsum += hv * lp[j];
        tps += expf(tsv);
    }
    __shared__ float red[6][256];
    red[0][tid] = lsum; red[1][tid] = tps;
    red[2][tid] = dps[0]; red[3][tid] = dps[1];
    red[4][tid] = dps[2]; red[5][tid] = dps[3];
    __syncthreads();
    for (int s = 128; s > 0; s >>= 1) {
        if (tid < s) {
#pragma unroll
            for (int q = 0; q < 6; ++q) red[q][tid] += red[q][tid + s];
        }
        __syncthreads();
    }
    if (tid == 0) {
        loss_part[i] = -red[0][0];
        float tp = red[1][0];
        float mx = fmaxf(fmaxf(red[2][0], red[3][0]), fmaxf(red[4][0], red[5][0]));
        acc_flag[i] = (tp >= mx) ? 1.f : 0.f;
    }
}

__global__ __launch_bounds__(256) void finalize_k(
    const float* __restrict__ loss_part, const float* __restrict__ acc_flag,
    float* __restrict__ out)
{
    int tid = threadIdx.x;
    float ls = 0.f, ac = 0.f;
    for (int i = tid; i < B_; i += 256) { ls += loss_part[i]; ac += acc_flag[i]; }
    __shared__ float s1[256], s2[256];
    s1[tid] = ls; s2[tid] = ac;
    __syncthreads();
    for (int s = 128; s > 0; s >>= 1) {
        if (tid < s) { s1[tid] += s1[tid + s]; s2[tid] += s2[tid + s]; }
        __syncthreads();
    }
    if (tid == 0) {
        out[0] = s1[0] / ((float)B_ * (float)B_);
        out[1] = s2[0] / (float)B_;
    }
}

// ---------------------------------------------------------------------------
// Host launcher
// ---------------------------------------------------------------------------
extern "C" void kernel_launch(void* const* d_in, const int* in_sizes, int n_in,
                              void* d_out, int out_size, void* d_ws, size_t ws_size,
                              hipStream_t stream)
{
    const float* target    = (const float*)d_in[0];
    const float* distract  = (const float*)d_in[1];
    const int*   start_tok = (const int*)d_in[2];
    const float* emb_s   = (const float*)d_in[4];
    const float* Wih_s   = (const float*)d_in[5];
    const float* Whh_s   = (const float*)d_in[6];
    const float* bih_s   = (const float*)d_in[7];
    const float* bhh_s   = (const float*)d_in[8];
    const float* aff_s_W = (const float*)d_in[9];
    const float* aff_s_b = (const float*)d_in[10];
    const float* probs_W = (const float*)d_in[11];
    const float* probs_b = (const float*)d_in[12];
    const float* emb_r   = (const float*)d_in[13];
    const float* Wih_r   = (const float*)d_in[14];
    const float* Whh_r   = (const float*)d_in[15];
    const float* bih_r   = (const float*)d_in[16];
    const float* bhh_r   = (const float*)d_in[17];
    const float* aff_r_W = (const float*)d_in[18];
    const float* aff_r_b = (const float*)d_in[19];

    float* ws = (float*)d_ws;
    // ---- base layout (identical to proven baseline; max footprint 119.7 MB)
    const size_t OFF_HS     = 0;
    const size_t OFF_CS     = 1048576;
    const size_t OFF_WE     = 2097152;
    const size_t OFF_GATES  = 2621440;
    const size_t OFF_HR     = 6815744;
    const size_t OFF_CR     = 7864320;
    const size_t OFF_LP     = 8912896;
    const size_t OFF_LOSSP  = 8916992;
    const size_t OFF_ACCF   = 8921088;
    const size_t OFF_MSG    = 8925184;
    const size_t OFF_LOGITS = 9437184;
    const size_t OFF_R      = 9437184;
    const size_t OFF_SC     = 13631488;
    // ---- bf16 plane region (float offsets; plane float-size = elems/2)
    const size_t OFF_PROBS_HI = 29917184;  // [VPAD,H] bf16
    const size_t OFF_PROBS_LO = 40206336;
    const size_t OFF_WIHS_HI  = 50495488;  // [4H,E]
    const size_t OFF_WIHS_LO  = 51544064;
    const size_t OFF_WHHS_HI  = 52592640;  // [4H,H]
    const size_t OFF_WHHS_LO  = 54689792;
    const size_t OFF_WIHR_HI  = 56786944;
    const size_t OFF_WIHR_LO  = 57835520;
    const size_t OFF_WHHR_HI  = 58884096;
    const size_t OFF_WHHR_LO  = 60981248;
    const size_t OFF_WEP_HI   = 63078400;  // [B,E]
    const size_t OFF_WEP_LO   = 63340544;
    const size_t OFF_HSP_HI   = 63602688;  // [B,H]
    const size_t OFF_HSP_LO   = 64126976;
    const size_t OFF_HRP_HI   = 64651264;  // [B,H]
    const size_t OFF_HRP_LO   = 65175552;
    const size_t TOTAL_FLOATS = 65699840;  // 262.8 MB

    float* h_s    = ws + OFF_HS;
    float* c_s    = ws + OFF_CS;
    float* w_e    = ws + OFF_WE;
    float* gates  = ws + OFF_GATES;
    float* h_r    = ws + OFF_HR;
    float* c_r    = ws + OFF_CR;
    float* lp     = ws + OFF_LP;
    float* lossp  = ws + OFF_LOSSP;
    float* accf   = ws + OFF_ACCF;
    int*   msg    = (int*)(ws + OFF_MSG);
    float* logits = ws + OFF_LOGITS;
    float* r_buf  = ws + OFF_R;
    float* sc     = ws + OFF_SC;

    auto gemm = [&](const float* A1, const float* W1, int K1,
                    const float* A2, const float* W2, int K2,
                    const float* b1, const float* b2,
                    float* C, int M, int N) {
        dim3 grid((N + BN - 1) / BN, M / BM);
        gemm_nt_split<<<grid, dim3(256), 0, stream>>>(A1, W1, K1, A2, W2, K2,
                                                      b1, b2, C, M, N);
    };

    const bool fast = ws_size >= TOTAL_FLOATS * sizeof(float);

    if (fast) {
        __bf16* probs_hi = (__bf16*)(ws + OFF_PROBS_HI);
        __bf16* probs_lo = (__bf16*)(ws + OFF_PROBS_LO);
        __bf16* wihs_hi  = (__bf16*)(ws + OFF_WIHS_HI);
        __bf16* wihs_lo  = (__bf16*)(ws + OFF_WIHS_LO);
        __bf16* whhs_hi  = (__bf16*)(ws + OFF_WHHS_HI);
        __bf16* whhs_lo  = (__bf16*)(ws + OFF_WHHS_LO);
        __bf16* wihr_hi  = (__bf16*)(ws + OFF_WIHR_HI);
        __bf16* wihr_lo  = (__bf16*)(ws + OFF_WIHR_LO);
        __bf16* whhr_hi  = (__bf16*)(ws + OFF_WHHR_HI);
        __bf16* whhr_lo  = (__bf16*)(ws + OFF_WHHR_LO);
        __bf16* we_hi    = (__bf16*)(ws + OFF_WEP_HI);
        __bf16* we_lo    = (__bf16*)(ws + OFF_WEP_LO);
        __bf16* hs_hi    = (__bf16*)(ws + OFF_HSP_HI);
        __bf16* hs_lo    = (__bf16*)(ws + OFF_HSP_LO);
        __bf16* hr_hi    = (__bf16*)(ws + OFF_HRP_HI);
        __bf16* hr_lo    = (__bf16*)(ws + OFF_HRP_LO);

        auto cvt = [&](const float* src, __bf16* hi, __bf16* lo, long n) {
            long n8 = n / 8;
            split_planes<<<(unsigned)((n8 + 255) / 256), 256, 0, stream>>>(
                src, hi, lo, n8);
        };
        auto gemmP = [&](const __bf16* Ah1, const __bf16* Al1,
                         const __bf16* Wh1, const __bf16* Wl1, int K1,
                         const __bf16* Ah2, const __bf16* Al2,
                         const __bf16* Wh2, const __bf16* Wl2, int K2,
                         const float* b1, const float* b2,
                         float* C, int M, int N) {
            dim3 grid((N + BN - 1) / BN, M / BM);
            gemm_nt_planes<<<grid, dim3(256), 0, stream>>>(
                Ah1, Al1, Wh1, Wl1, K1, Ah2, Al2, Wh2, Wl2, K2, b1, b2, C, M, N);
        };

        // ---- one-time weight plane conversions (~45 us total)
        cvt(probs_W, probs_hi, probs_lo, (long)V_ * H_);
        cvt(Wih_s, wihs_hi, wihs_lo, (long)4 * H_ * E_);
        cvt(Whh_s, whhs_hi, whhs_lo, (long)4 * H_ * H_);
        cvt(Wih_r, wihr_hi, wihr_lo, (long)4 * H_ * E_);
        cvt(Whh_r, whhr_hi, whhr_lo, (long)4 * H_ * H_);
        // zero probs pad rows (20000..20095) for determinism
        {
            int padn = (VPAD - V_) * H_ / 2;  // floats
            zero_f32<<<(padn + 255) / 256, 256, 0, stream>>>(
                ws + OFF_PROBS_HI + (size_t)V_ * H_ / 2, padn);
            zero_f32<<<(padn + 255) / 256, 256, 0, stream>>>(
                ws + OFF_PROBS_LO + (size_t)V_ * H_ / 2, padn);
        }

        // ---- Sender ----
        gemm(target, aff_s_W, F_, nullptr, nullptr, 0, aff_s_b, nullptr, h_s, B_, H_);
        cvt(h_s, hs_hi, hs_lo, (long)B_ * H_);
        zero_f32<<<(B_ * H_ + 255) / 256, 256, 0, stream>>>(c_s, B_ * H_);
        broadcast_emb_planes<<<B_, 64, 0, stream>>>(emb_s, start_tok, we_hi, we_lo);

        for (int t = 0; t < L_; ++t) {
            gemmP(we_hi, we_lo, wihs_hi, wihs_lo, E_,
                  hs_hi, hs_lo, whhs_hi, whhs_lo, H_,
                  bih_s, bhh_s, gates, B_, 4 * H_);
            lstm_pointwise<<<(B_ * H_ + 255) / 256, 256, 0, stream>>>(
                gates, c_s, h_s, hs_hi, hs_lo);
            gemmP(hs_hi, hs_lo, probs_hi, probs_lo, H_,
                  nullptr, nullptr, nullptr, nullptr, 0,
                  probs_b, nullptr, logits, B_, V_);
            row_argmax_lse<<<B_, 256, 0, stream>>>(logits, msg + (size_t)t * B_, lp,
                                                   (t == L_ - 1) ? 1 : 0);
            if (t < L_ - 1)
                gather_emb_planes<<<B_, 64, 0, stream>>>(emb_s, msg + (size_t)t * B_,
                                                         we_hi, we_lo);
        }

        // ---- Receiver ----
        zero_f32<<<(B_ * H_ + 255) / 256, 256, 0, stream>>>(h_r, B_ * H_);
        zero_f32<<<(B_ * H_ + 255) / 256, 256, 0, stream>>>(c_r, B_ * H_);
        zero_f32<<<(B_ * H_ / 2 + 255) / 256, 256, 0, stream>>>(
            ws + OFF_HRP_HI, B_ * H_ / 2);
        zero_f32<<<(B_ * H_ / 2 + 255) / 256, 256, 0, stream>>>(
            ws + OFF_HRP_LO, B_ * H_ / 2);
        for (int t = 0; t < L_; ++t) {
            gather_emb_planes<<<B_, 64, 0, stream>>>(emb_r, msg + (size_t)t * B_,
                                                     we_hi, we_lo);
            gemmP(we_hi, we_lo, wihr_hi, wihr_lo, E_,
                  hr_hi, hr_lo, whhr_hi, whhr_lo, H_,
                  bih_r, bhh_r, gates, B_, 4 * H_);
            lstm_pointwise<<<(B_ * H_ + 255) / 256, 256, 0, stream>>>(
                gates, c_r, h_r, hr_hi, hr_lo);
        }
    } else {
        // ---- fallback: proven fp32-split path (ws too small for planes)
        gemm(target, aff_s_W, F_, nullptr, nullptr, 0, aff_s_b, nullptr, h_s, B_, H_);
        zero_f32<<<(B_ * H_ + 255) / 256, 256, 0, stream>>>(c_s, B_ * H_);
        broadcast_emb<<<B_, 128, 0, stream>>>(emb_s, start_tok, w_e);

        for (int t = 0; t < L_; ++t) {
            gemm(w_e, Wih_s, E_, h_s, Whh_s, H_, bih_s, bhh_s, gates, B_, 4 * H_);
            lstm_pointwise<<<(B_ * H_ + 255) / 256, 256, 0, stream>>>(
                gates, c_s, h_s, nullptr, nullptr);
            gemm(h_s, probs_W, H_, nullptr, nullptr, 0, probs_b, nullptr,
                 logits, B_, V_);
            row_argmax_lse<<<B_, 256, 0, stream>>>(logits, msg + (size_t)t * B_, lp,
                                                   (t == L_ - 1) ? 1 : 0);
            if (t < L_ - 1)
                gather_emb<<<B_, 128, 0, stream>>>(emb_s, msg + (size_t)t * B_, w_e);
        }

        zero_f32<<<(B_ * H_ + 255) / 256, 256, 0, stream>>>(h_r, B_ * H_);
        zero_f32<<<(B_ * H_ + 255) / 256, 256, 0, stream>>>(c_r, B_ * H_);
        for (int t = 0; t < L_; ++t) {
            gather_emb<<<B_, 128, 0, stream>>>(emb_r, msg + (size_t)t * B_, w_e);
            gemm(w_e, Wih_r, E_, h_r, Whh_r, H_, bih_r, bhh_r, gates, B_, 4 * H_);
            lstm_pointwise<<<(B_ * H_ + 255) / 256, 256, 0, stream>>>(
                gates, c_r, h_r, nullptr, nullptr);
        }
    }

    // ---- tail (common): r, scores, loss ----
    gemm(h_r, aff_r_W, H_, nullptr, nullptr, 0, aff_r_b, nullptr, r_buf, B_, F_);
    gemm(target, r_buf, F_, nullptr, nullptr, 0, nullptr, nullptr, sc, B_, B_);
    gemm(distract, r_buf, F_, nullptr, nullptr, 0, nullptr, nullptr,
         sc + (size_t)B_ * B_, D_ * B_, B_);

    loss_rows<<<B_, 256, 0, stream>>>(sc, lp, lossp, accf);
    finalize_k<<<1, 256, 0, stream>>>(lossp, accf, (float*)d_out);
}

// Round 4
// 6717.945 us; speedup vs baseline: 1.2248x; 1.1111x over previous
//
#include <hip/hip_runtime.h>
#include <cmath>

// Problem constants (fixed by the reference file)
#define B_ 1024
#define F_ 4096
#define V_ 20000
#define E_ 512
#define H_ 1024
#define L_ 20
#define D_ 4

typedef __bf16 bf16x8 __attribute__((ext_vector_type(8)));
typedef float  f32x4  __attribute__((ext_vector_type(4)));

#define BM 128
#define BN 128
#define BK 32

// padded row count for probs planes so loads need no guard (157*128)
#define VPAD 20096

// ---------------------------------------------------------------------------
// Block remap: HW dispatches blockIdx.x-fastest, round-robin across 8 XCDs.
// We remap to (1) M-major logical order so consecutive logical blocks share
// the same N-panel (the big W operand) and (2) XCD-chunked (bijective, m204)
// so each XCD owns a CONTIGUOUS logical range -> W-panel is fetched once into
// that XCD's L2 and reused by all its M-tiles. A (<=4MB planes) L2-fits anyway.
// ---------------------------------------------------------------------------
__device__ __forceinline__ void remap_block(int& bm, int& bn)
{
    const int nbx  = gridDim.x;            // N tiles
    const int nby  = gridDim.y;            // M tiles
    const int nwg  = nbx * nby;
    const int flat = blockIdx.y * nbx + blockIdx.x;  // HW dispatch rank
    const int q = nwg >> 3, r = nwg & 7;
    const int xcd = flat & 7, lead = flat >> 3;
    const int wgid = (xcd < r ? xcd * (q + 1) : r * (q + 1) + (xcd - r) * q) + lead;
    bm = (wgid % nby) * BM;                // M-major: M varies fastest
    bn = (wgid / nby) * BN;
}

// ---------------------------------------------------------------------------
// async global->LDS, 16B per lane. LDS dest is wave-uniform base + lane*16:
// our linear [rows][32]bf16 layout with thread t -> byte t*16 satisfies that.
// ---------------------------------------------------------------------------
__device__ __forceinline__ void gld_lds16(const void* g, void* l)
{
    __builtin_amdgcn_global_load_lds(
        (const __attribute__((address_space(1))) void*)g,
        (__attribute__((address_space(3))) void*)l, 16, 0, 0);
}

// ---------------------------------------------------------------------------
// OLD proven kernel: fp32 inputs, in-staging bf16 hi/lo split, 3 MFMAs/chunk.
// Kept for one-shot GEMMs (h0, aff_r, score mats) and the ws_size fallback.
// ---------------------------------------------------------------------------
__global__ __launch_bounds__(256, 2) void gemm_nt_split(
    const float* __restrict__ A1, const float* __restrict__ W1, int K1,
    const float* __restrict__ A2, const float* __restrict__ W2, int K2,
    const float* __restrict__ b1, const float* __restrict__ b2,
    float* __restrict__ C, int M, int N)
{
    __shared__ __align__(16) __bf16 As_hi[BM][BK];
    __shared__ __align__(16) __bf16 As_lo[BM][BK];
    __shared__ __align__(16) __bf16 Ws_hi[BN][BK];
    __shared__ __align__(16) __bf16 Ws_lo[BN][BK];

    const int tid  = threadIdx.x;
    int bm, bn;
    remap_block(bm, bn);
    const int srow = tid >> 1;
    const int scol = (tid & 1) * 16;
    const int lane = tid & 63;
    const int wv   = tid >> 6;
    const int wm   = (wv & 1) * 64;
    const int wn   = (wv >> 1) * 64;
    const int fm   = lane & 15;
    const int fq   = lane >> 4;

    const bool wok = (bn + srow) < N;

    f32x4 acc[4][4];
#pragma unroll
    for (int i = 0; i < 4; ++i)
#pragma unroll
        for (int j = 0; j < 4; ++j) acc[i][j] = (f32x4){0.f, 0.f, 0.f, 0.f};

#pragma unroll 1
    for (int s = 0; s < 2; ++s) {
        const float* A = s ? A2 : A1;
        const float* W = s ? W2 : W1;
        const int    K = s ? K2 : K1;
        if (!A) continue;
        const float* Arow = A + (size_t)(bm + srow) * K;
        const float* Wrow = W + (size_t)(bn + srow) * K;

        for (int k0 = 0; k0 < K; k0 += BK) {
            float av[16], wvv[16];
            const float* ap = Arow + k0 + scol;
            *(float4*)&av[0]   = *(const float4*)(ap + 0);
            *(float4*)&av[4]   = *(const float4*)(ap + 4);
            *(float4*)&av[8]   = *(const float4*)(ap + 8);
            *(float4*)&av[12]  = *(const float4*)(ap + 12);
            if (wok) {
                const float* wp = Wrow + k0 + scol;
                *(float4*)&wvv[0]  = *(const float4*)(wp + 0);
                *(float4*)&wvv[4]  = *(const float4*)(wp + 4);
                *(float4*)&wvv[8]  = *(const float4*)(wp + 8);
                *(float4*)&wvv[12] = *(const float4*)(wp + 12);
            } else {
#pragma unroll
                for (int v = 0; v < 16; ++v) wvv[v] = 0.f;
            }
            __syncthreads();

#pragma unroll
            for (int u = 0; u < 16; u += 8) {
                bf16x8 hh, ll;
#pragma unroll
                for (int v = 0; v < 8; ++v) {
                    float x = av[u + v];
                    __bf16 h = (__bf16)x;
                    hh[v] = h;
                    ll[v] = (__bf16)(x - (float)h);
                }
                *(bf16x8*)&As_hi[srow][scol + u] = hh;
                *(bf16x8*)&As_lo[srow][scol + u] = ll;
            }
#pragma unroll
            for (int u = 0; u < 16; u += 8) {
                bf16x8 hh, ll;
#pragma unroll
                for (int v = 0; v < 8; ++v) {
                    float x = wvv[u + v];
                    __bf16 h = (__bf16)x;
                    hh[v] = h;
                    ll[v] = (__bf16)(x - (float)h);
                }
                *(bf16x8*)&Ws_hi[srow][scol + u] = hh;
                *(bf16x8*)&Ws_lo[srow][scol + u] = ll;
            }
            __syncthreads();

            bf16x8 ah[4], al[4];
#pragma unroll
            for (int i = 0; i < 4; ++i) {
                ah[i] = *(const bf16x8*)&As_hi[wm + i * 16 + fm][fq * 8];
                al[i] = *(const bf16x8*)&As_lo[wm + i * 16 + fm][fq * 8];
            }
#pragma unroll
            for (int j = 0; j < 4; ++j) {
                bf16x8 bh = *(const bf16x8*)&Ws_hi[wn + j * 16 + fm][fq * 8];
                bf16x8 bl = *(const bf16x8*)&Ws_lo[wn + j * 16 + fm][fq * 8];
#pragma unroll
                for (int i = 0; i < 4; ++i) {
                    acc[i][j] = __builtin_amdgcn_mfma_f32_16x16x32_bf16(
                        al[i], bh, acc[i][j], 0, 0, 0);
                    acc[i][j] = __builtin_amdgcn_mfma_f32_16x16x32_bf16(
                        ah[i], bl, acc[i][j], 0, 0, 0);
                    acc[i][j] = __builtin_amdgcn_mfma_f32_16x16x32_bf16(
                        ah[i], bh, acc[i][j], 0, 0, 0);
                }
            }
        }
    }

#pragma unroll
    for (int j = 0; j < 4; ++j) {
        int col = bn + wn + j * 16 + fm;
        if (col >= N) continue;
        float badd = (b1 ? b1[col] : 0.f) + (b2 ? b2[col] : 0.f);
#pragma unroll
        for (int i = 0; i < 4; ++i) {
            int row0 = bm + wm + i * 16 + fq * 4;
            f32x4 v = acc[i][j];
#pragma unroll
            for (int r = 0; r < 4; ++r)
                C[(size_t)(row0 + r) * N + col] = v[r] + badd;
        }
    }
}

// ---------------------------------------------------------------------------
// Plane GEMM. A/W pre-split into persistent bf16 hi/lo planes.
// global_load_lds staging (no VALU conversion, no reg round-trip).
// W planes row-padded to a multiple of 128 (no load guard; garbage pad rows
// only reach store-guarded C columns).
// Same 3-MFMA split math and chunk order as gemm_nt_split -> identical bits.
// ---------------------------------------------------------------------------
__global__ __launch_bounds__(256, 3) void gemm_nt_planes(
    const __bf16* __restrict__ Ah1, const __bf16* __restrict__ Al1,
    const __bf16* __restrict__ Wh1, const __bf16* __restrict__ Wl1, int K1,
    const __bf16* __restrict__ Ah2, const __bf16* __restrict__ Al2,
    const __bf16* __restrict__ Wh2, const __bf16* __restrict__ Wl2, int K2,
    const float* __restrict__ b1, const float* __restrict__ b2,
    float* __restrict__ C, int M, int N)
{
    __shared__ __align__(16) __bf16 As_hi[BM][BK];
    __shared__ __align__(16) __bf16 As_lo[BM][BK];
    __shared__ __align__(16) __bf16 Ws_hi[BN][BK];
    __shared__ __align__(16) __bf16 Ws_lo[BN][BK];

    const int tid  = threadIdx.x;
    int bm, bn;
    remap_block(bm, bn);
    // staging: thread t -> row t>>2 (0..63, +64 on 2nd issue), 8-elem col slot
    // LDS byte offset = tid*16 (wave-uniform base + lane*16 -> legal for
    // global_load_lds direct staging)
    const int srow = tid >> 2;
    const int scol = (tid & 3) * 8;
    const int lane = tid & 63;
    const int wv   = tid >> 6;
    const int wm   = (wv & 1) * 64;
    const int wn   = (wv >> 1) * 64;
    const int fm   = lane & 15;
    const int fq   = lane >> 4;

    f32x4 acc[4][4];
#pragma unroll
    for (int i = 0; i < 4; ++i)
#pragma unroll
        for (int j = 0; j < 4; ++j) acc[i][j] = (f32x4){0.f, 0.f, 0.f, 0.f};

#pragma unroll 1
    for (int s = 0; s < 2; ++s) {
        const __bf16* Ah = s ? Ah2 : Ah1;
        const __bf16* Al = s ? Al2 : Al1;
        const __bf16* Wh = s ? Wh2 : Wh1;
        const __bf16* Wl = s ? Wl2 : Wl1;
        const int     K  = s ? K2  : K1;
        if (!Ah) continue;
        const size_t aoff  = (size_t)(bm + srow) * K + scol;
        const size_t woff  = (size_t)(bn + srow) * K + scol;
        const size_t step  = (size_t)64 * K;

        for (int k0 = 0; k0 < K; k0 += BK) {
            __syncthreads();   // all waves done reading previous chunk
            gld_lds16(Ah + aoff + k0,        &As_hi[srow][scol]);
            gld_lds16(Ah + aoff + k0 + step, &As_hi[srow + 64][scol]);
            gld_lds16(Al + aoff + k0,        &As_lo[srow][scol]);
            gld_lds16(Al + aoff + k0 + step, &As_lo[srow + 64][scol]);
            gld_lds16(Wh + woff + k0,        &Ws_hi[srow][scol]);
            gld_lds16(Wh + woff + k0 + step, &Ws_hi[srow + 64][scol]);
            gld_lds16(Wl + woff + k0,        &Ws_lo[srow][scol]);
            gld_lds16(Wl + woff + k0 + step, &Ws_lo[srow + 64][scol]);
            __syncthreads();   // compiler drains vmcnt(0) before s_barrier

            bf16x8 ah[4], al[4];
#pragma unroll
            for (int i = 0; i < 4; ++i) {
                ah[i] = *(const bf16x8*)&As_hi[wm + i * 16 + fm][fq * 8];
                al[i] = *(const bf16x8*)&As_lo[wm + i * 16 + fm][fq * 8];
            }
#pragma unroll
            for (int j = 0; j < 4; ++j) {
                bf16x8 bh = *(const bf16x8*)&Ws_hi[wn + j * 16 + fm][fq * 8];
                bf16x8 bl = *(const bf16x8*)&Ws_lo[wn + j * 16 + fm][fq * 8];
#pragma unroll
                for (int i = 0; i < 4; ++i) {
                    acc[i][j] = __builtin_amdgcn_mfma_f32_16x16x32_bf16(
                        al[i], bh, acc[i][j], 0, 0, 0);
                    acc[i][j] = __builtin_amdgcn_mfma_f32_16x16x32_bf16(
                        ah[i], bl, acc[i][j], 0, 0, 0);
                    acc[i][j] = __builtin_amdgcn_mfma_f32_16x16x32_bf16(
                        ah[i], bh, acc[i][j], 0, 0, 0);
                }
            }
        }
    }

#pragma unroll
    for (int j = 0; j < 4; ++j) {
        int col = bn + wn + j * 16 + fm;
        if (col >= N) continue;
        float badd = (b1 ? b1[col] : 0.f) + (b2 ? b2[col] : 0.f);
#pragma unroll
        for (int i = 0; i < 4; ++i) {
            int row0 = bm + wm + i * 16 + fq * 4;
            f32x4 v = acc[i][j];
#pragma unroll
            for (int r = 0; r < 4; ++r)
                C[(size_t)(row0 + r) * N + col] = v[r] + badd;
        }
    }
}

// ---------------------------------------------------------------------------
// fp32 -> bf16 hi/lo plane split, 8 elems/thread
// ---------------------------------------------------------------------------
__global__ __launch_bounds__(256) void split_planes(
    const float* __restrict__ src, __bf16* __restrict__ hi,
    __bf16* __restrict__ lo, long n8)
{
    long i = (long)blockIdx.x * 256 + threadIdx.x;
    if (i >= n8) return;
    float4 a = ((const float4*)src)[2 * i];
    float4 b = ((const float4*)src)[2 * i + 1];
    float v[8] = {a.x, a.y, a.z, a.w, b.x, b.y, b.z, b.w};
    bf16x8 hh, ll;
#pragma unroll
    for (int j = 0; j < 8; ++j) {
        float x = v[j];
        __bf16 h = (__bf16)x;
        hh[j] = h;
        ll[j] = (__bf16)(x - (float)h);
    }
    ((bf16x8*)hi)[i] = hh;
    ((bf16x8*)lo)[i] = ll;
}

// ---------------------------------------------------------------------------
// LSTM pointwise; optionally emits h as bf16 hi/lo planes (free conversion)
// ---------------------------------------------------------------------------
__global__ __launch_bounds__(256) void lstm_pointwise(
    const float* __restrict__ gates, float* __restrict__ c, float* __restrict__ h,
    __bf16* __restrict__ hhi, __bf16* __restrict__ hlo)
{
    int i = blockIdx.x * blockDim.x + threadIdx.x;
    if (i >= B_ * H_) return;
    int b = i / H_, k = i % H_;
    const float* g = gates + (size_t)b * 4 * H_;
    float gi = g[k], gf = g[H_ + k], gg = g[2 * H_ + k], go = g[3 * H_ + k];
    float si = 1.f / (1.f + expf(-gi));
    float sf = 1.f / (1.f + expf(-gf));
    float so = 1.f / (1.f + expf(-go));
    float cn = sf * c[i] + si * tanhf(gg);
    c[i] = cn;
    float hv = so * tanhf(cn);
    h[i] = hv;
    if (hhi) {
        __bf16 hh = (__bf16)hv;
        hhi[i] = hh;
        hlo[i] = (__bf16)(hv - (float)hh);
    }
}

// ---------------------------------------------------------------------------
// Per-row argmax (first-occurrence) + online logsumexp. float4 loads (G13).
// ---------------------------------------------------------------------------
__global__ __launch_bounds__(256) void row_argmax_lse(
    const float* __restrict__ logits, int* __restrict__ tok,
    float* __restrict__ lp, int need_lp)
{
    int b = blockIdx.x;
    const float4* row4 = (const float4*)(logits + (size_t)b * V_);
    int tid = threadIdx.x;
    float m = -INFINITY; int mi = 0;
    float lm = -INFINITY, ls = 0.f;
    for (int j4 = tid; j4 < V_ / 4; j4 += 256) {
        float4 q = row4[j4];
        float vv[4] = {q.x, q.y, q.z, q.w};
#pragma unroll
        for (int u = 0; u < 4; ++u) {
            float v = vv[u];
            if (v > m) { m = v; mi = j4 * 4 + u; }
            if (need_lp) {
                if (v > lm) { ls = ls * expf(lm - v) + 1.f; lm = v; }
                else ls += expf(v - lm);
            }
        }
    }
    __shared__ float sm[256]; __shared__ int si[256];
    __shared__ float slm[256], sls[256];
    sm[tid] = m; si[tid] = mi; slm[tid] = lm; sls[tid] = ls;
    __syncthreads();
    for (int s = 128; s > 0; s >>= 1) {
        if (tid < s) {
            float vm = sm[tid + s]; int vi = si[tid + s];
            if (vm > sm[tid] || (vm == sm[tid] && vi < si[tid])) {
                sm[tid] = vm; si[tid] = vi;
            }
            if (need_lp) {
                float am = slm[tid], as = sls[tid];
                float bm2 = slm[tid + s], bs = sls[tid + s];
                if (am >= bm2) {
                    sls[tid] = as + bs * expf(bm2 - am);
                } else {
                    sls[tid] = bs + as * expf(am - bm2);
                    slm[tid] = bm2;
                }
            }
        }
        __syncthreads();
    }
    if (tid == 0) {
        tok[b] = si[0];
        if (need_lp) lp[b] = sm[0] - (slm[0] + logf(sls[0]));
    }
}

// ---------------------------------------------------------------------------
// Embedding gathers (fp32 versions for fallback; plane versions for fast path)
// ---------------------------------------------------------------------------
__global__ __launch_bounds__(128) void gather_emb(
    const float* __restrict__ emb, const int* __restrict__ tok,
    float* __restrict__ out)
{
    int b = blockIdx.x;
    int t = tok[b];
    const float4* src = (const float4*)(emb + (size_t)t * E_);
    float4* dst = (float4*)(out + (size_t)b * E_);
    for (int e = threadIdx.x; e < E_ / 4; e += blockDim.x) dst[e] = src[e];
}

__global__ __launch_bounds__(128) void broadcast_emb(
    const float* __restrict__ emb, const int* __restrict__ sidx,
    float* __restrict__ out)
{
    int b = blockIdx.x;
    int t = sidx[0];
    const float4* src = (const float4*)(emb + (size_t)t * E_);
    float4* dst = (float4*)(out + (size_t)b * E_);
    for (int e = threadIdx.x; e < E_ / 4; e += blockDim.x) dst[e] = src[e];
}

__device__ __forceinline__ void emb_row_split(
    const float* __restrict__ emb, int t, int b, int i,
    __bf16* __restrict__ whi, __bf16* __restrict__ wlo)
{
    const float4* src = (const float4*)(emb + (size_t)t * E_);
    float4 a = src[2 * i], c2 = src[2 * i + 1];
    float v[8] = {a.x, a.y, a.z, a.w, c2.x, c2.y, c2.z, c2.w};
    bf16x8 hh, ll;
#pragma unroll
    for (int j = 0; j < 8; ++j) {
        float x = v[j];
        __bf16 h = (__bf16)x;
        hh[j] = h;
        ll[j] = (__bf16)(x - (float)h);
    }
    ((bf16x8*)(whi + (size_t)b * E_))[i] = hh;
    ((bf16x8*)(wlo + (size_t)b * E_))[i] = ll;
}

__global__ __launch_bounds__(64) void gather_emb_planes(
    const float* __restrict__ emb, const int* __restrict__ tok,
    __bf16* __restrict__ whi, __bf16* __restrict__ wlo)
{
    emb_row_split(emb, tok[blockIdx.x], blockIdx.x, threadIdx.x, whi, wlo);
}

__global__ __launch_bounds__(64) void broadcast_emb_planes(
    const float* __restrict__ emb, const int* __restrict__ sidx,
    __bf16* __restrict__ whi, __bf16* __restrict__ wlo)
{
    emb_row_split(emb, sidx[0], blockIdx.x, threadIdx.x, whi, wlo);
}

__global__ __launch_bounds__(256) void zero_f32(float* __restrict__ p, int n)
{
    int i = blockIdx.x * blockDim.x + threadIdx.x;
    if (i < n) p[i] = 0.f;
}

// ---------------------------------------------------------------------------
// Loss rows + finalize (unchanged)
// ---------------------------------------------------------------------------
__global__ __launch_bounds__(256) void loss_rows(
    const float* __restrict__ sc, const float* __restrict__ lp,
    float* __restrict__ loss_part, float* __restrict__ acc_flag)
{
    int i = blockIdx.x; int tid = threadIdx.x;
    const float* tsrow = sc + (size_t)i * B_;
    float lsum = 0.f, tps = 0.f;
    float dps[4] = {0.f, 0.f, 0.f, 0.f};
    for (int j = tid; j < B_; j += 256) {
        float tsv = tsrow[j];
        float hv = 0.f;
#pragma unroll
        for (int d = 0; d < 4; ++d) {
            float dv = sc[((size_t)(1 + d) * B_ + i) * B_ + j];
            float t = 1.f - tsv + dv;
            hv += (t > 0.f) ? t : 0.f;
            dps[d] += expf(dv);
        }
        lsum += hv * lp[j];
        tps += expf(tsv);
    }
    __shared__ float red[6][256];
    red[0][tid] = lsum; red[1][tid] = tps;
    red[2][tid] = dps[0]; red[3][tid] = dps[1];
    red[4][tid] = dps[2]; red[5][tid] = dps[3];
    __syncthreads();
    for (int s = 128; s > 0; s >>= 1) {
        if (tid < s) {
#pragma unroll
            for (int q = 0; q < 6; ++q) red[q][tid] += red[q][tid + s];
        }
        __syncthreads();
    }
    if (tid == 0) {
        loss_part[i] = -red[0][0];
        float tp = red[1][0];
        float mx = fmaxf(fmaxf(red[2][0], red[3][0]), fmaxf(red[4][0], red[5][0]));
        acc_flag[i] = (tp >= mx) ? 1.f : 0.f;
    }
}

__global__ __launch_bounds__(256) void finalize_k(
    const float* __restrict__ loss_part, const float* __restrict__ acc_flag,
    float* __restrict__ out)
{
    int tid = threadIdx.x;
    float ls = 0.f, ac = 0.f;
    for (int i = tid; i < B_; i += 256) { ls += loss_part[i]; ac += acc_flag[i]; }
    __shared__ float s1[256], s2[256];
    s1[tid] = ls; s2[tid] = ac;
    __syncthreads();
    for (int s = 128; s > 0; s >>= 1) {
        if (tid < s) { s1[tid] += s1[tid + s]; s2[tid] += s2[tid + s]; }
        __syncthreads();
    }
    if (tid == 0) {
        out[0] = s1[0] / ((float)B_ * (float)B_);
        out[1] = s2[0] / (float)B_;
    }
}

// ---------------------------------------------------------------------------
// Host launcher
// ---------------------------------------------------------------------------
extern "C" void kernel_launch(void* const* d_in, const int* in_sizes, int n_in,
                              void* d_out, int out_size, void* d_ws, size_t ws_size,
                              hipStream_t stream)
{
    const float* target    = (const float*)d_in[0];
    const float* distract  = (const float*)d_in[1];
    const int*   start_tok = (const int*)d_in[2];
    const float* emb_s   = (const float*)d_in[4];
    const float* Wih_s   = (const float*)d_in[5];
    const float* Whh_s   = (const float*)d_in[6];
    const float* bih_s   = (const float*)d_in[7];
    const float* bhh_s   = (const float*)d_in[8];
    const float* aff_s_W = (const float*)d_in[9];
    const float* aff_s_b = (const float*)d_in[10];
    const float* probs_W = (const float*)d_in[11];
    const float* probs_b = (const float*)d_in[12];
    const float* emb_r   = (const float*)d_in[13];
    const float* Wih_r   = (const float*)d_in[14];
    const float* Whh_r   = (const float*)d_in[15];
    const float* bih_r   = (const float*)d_in[16];
    const float* bhh_r   = (const float*)d_in[17];
    const float* aff_r_W = (const float*)d_in[18];
    const float* aff_r_b = (const float*)d_in[19];

    float* ws = (float*)d_ws;
    // ---- base layout (identical to proven baseline; max footprint 119.7 MB)
    const size_t OFF_HS     = 0;
    const size_t OFF_CS     = 1048576;
    const size_t OFF_WE     = 2097152;
    const size_t OFF_GATES  = 2621440;
    const size_t OFF_HR     = 6815744;
    const size_t OFF_CR     = 7864320;
    const size_t OFF_LP     = 8912896;
    const size_t OFF_LOSSP  = 8916992;
    const size_t OFF_ACCF   = 8921088;
    const size_t OFF_MSG    = 8925184;
    const size_t OFF_LOGITS = 9437184;
    const size_t OFF_R      = 9437184;
    const size_t OFF_SC     = 13631488;
    // ---- bf16 plane region (float offsets; plane float-size = elems/2)
    const size_t OFF_PROBS_HI = 29917184;  // [VPAD,H] bf16
    const size_t OFF_PROBS_LO = 40206336;
    const size_t OFF_WIHS_HI  = 50495488;  // [4H,E]
    const size_t OFF_WIHS_LO  = 51544064;
    const size_t OFF_WHHS_HI  = 52592640;  // [4H,H]
    const size_t OFF_WHHS_LO  = 54689792;
    const size_t OFF_WIHR_HI  = 56786944;
    const size_t OFF_WIHR_LO  = 57835520;
    const size_t OFF_WHHR_HI  = 58884096;
    const size_t OFF_WHHR_LO  = 60981248;
    const size_t OFF_WEP_HI   = 63078400;  // [B,E]
    const size_t OFF_WEP_LO   = 63340544;
    const size_t OFF_HSP_HI   = 63602688;  // [B,H]
    const size_t OFF_HSP_LO   = 64126976;
    const size_t OFF_HRP_HI   = 64651264;  // [B,H]
    const size_t OFF_HRP_LO   = 65175552;
    const size_t TOTAL_FLOATS = 65699840;  // 262.8 MB

    float* h_s    = ws + OFF_HS;
    float* c_s    = ws + OFF_CS;
    float* w_e    = ws + OFF_WE;
    float* gates  = ws + OFF_GATES;
    float* h_r    = ws + OFF_HR;
    float* c_r    = ws + OFF_CR;
    float* lp     = ws + OFF_LP;
    float* lossp  = ws + OFF_LOSSP;
    float* accf   = ws + OFF_ACCF;
    int*   msg    = (int*)(ws + OFF_MSG);
    float* logits = ws + OFF_LOGITS;
    float* r_buf  = ws + OFF_R;
    float* sc     = ws + OFF_SC;

    auto gemm = [&](const float* A1, const float* W1, int K1,
                    const float* A2, const float* W2, int K2,
                    const float* b1, const float* b2,
                    float* C, int M, int N) {
        dim3 grid((N + BN - 1) / BN, M / BM);
        gemm_nt_split<<<grid, dim3(256), 0, stream>>>(A1, W1, K1, A2, W2, K2,
                                                      b1, b2, C, M, N);
    };

    const bool fast = ws_size >= TOTAL_FLOATS * sizeof(float);

    if (fast) {
        __bf16* probs_hi = (__bf16*)(ws + OFF_PROBS_HI);
        __bf16* probs_lo = (__bf16*)(ws + OFF_PROBS_LO);
        __bf16* wihs_hi  = (__bf16*)(ws + OFF_WIHS_HI);
        __bf16* wihs_lo  = (__bf16*)(ws + OFF_WIHS_LO);
        __bf16* whhs_hi  = (__bf16*)(ws + OFF_WHHS_HI);
        __bf16* whhs_lo  = (__bf16*)(ws + OFF_WHHS_LO);
        __bf16* wihr_hi  = (__bf16*)(ws + OFF_WIHR_HI);
        __bf16* wihr_lo  = (__bf16*)(ws + OFF_WIHR_LO);
        __bf16* whhr_hi  = (__bf16*)(ws + OFF_WHHR_HI);
        __bf16* whhr_lo  = (__bf16*)(ws + OFF_WHHR_LO);
        __bf16* we_hi    = (__bf16*)(ws + OFF_WEP_HI);
        __bf16* we_lo    = (__bf16*)(ws + OFF_WEP_LO);
        __bf16* hs_hi    = (__bf16*)(ws + OFF_HSP_HI);
        __bf16* hs_lo    = (__bf16*)(ws + OFF_HSP_LO);
        __bf16* hr_hi    = (__bf16*)(ws + OFF_HRP_HI);
        __bf16* hr_lo    = (__bf16*)(ws + OFF_HRP_LO);

        auto cvt = [&](const float* src, __bf16* hi, __bf16* lo, long n) {
            long n8 = n / 8;
            split_planes<<<(unsigned)((n8 + 255) / 256), 256, 0, stream>>>(
                src, hi, lo, n8);
        };
        auto gemmP = [&](const __bf16* Ah1, const __bf16* Al1,
                         const __bf16* Wh1, const __bf16* Wl1, int K1,
                         const __bf16* Ah2, const __bf16* Al2,
                         const __bf16* Wh2, const __bf16* Wl2, int K2,
                         const float* b1, const float* b2,
                         float* C, int M, int N) {
            dim3 grid((N + BN - 1) / BN, M / BM);
            gemm_nt_planes<<<grid, dim3(256), 0, stream>>>(
                Ah1, Al1, Wh1, Wl1, K1, Ah2, Al2, Wh2, Wl2, K2, b1, b2, C, M, N);
        };

        // ---- one-time weight plane conversions (~45 us total)
        cvt(probs_W, probs_hi, probs_lo, (long)V_ * H_);
        cvt(Wih_s, wihs_hi, wihs_lo, (long)4 * H_ * E_);
        cvt(Whh_s, whhs_hi, whhs_lo, (long)4 * H_ * H_);
        cvt(Wih_r, wihr_hi, wihr_lo, (long)4 * H_ * E_);
        cvt(Whh_r, whhr_hi, whhr_lo, (long)4 * H_ * H_);
        // zero probs pad rows (20000..20095) for determinism
        {
            int padn = (VPAD - V_) * H_ / 2;  // floats
            zero_f32<<<(padn + 255) / 256, 256, 0, stream>>>(
                ws + OFF_PROBS_HI + (size_t)V_ * H_ / 2, padn);
            zero_f32<<<(padn + 255) / 256, 256, 0, stream>>>(
                ws + OFF_PROBS_LO + (size_t)V_ * H_ / 2, padn);
        }

        // ---- Sender ----
        gemm(target, aff_s_W, F_, nullptr, nullptr, 0, aff_s_b, nullptr, h_s, B_, H_);
        cvt(h_s, hs_hi, hs_lo, (long)B_ * H_);
        zero_f32<<<(B_ * H_ + 255) / 256, 256, 0, stream>>>(c_s, B_ * H_);
        broadcast_emb_planes<<<B_, 64, 0, stream>>>(emb_s, start_tok, we_hi, we_lo);

        for (int t = 0; t < L_; ++t) {
            gemmP(we_hi, we_lo, wihs_hi, wihs_lo, E_,
                  hs_hi, hs_lo, whhs_hi, whhs_lo, H_,
                  bih_s, bhh_s, gates, B_, 4 * H_);
            lstm_pointwise<<<(B_ * H_ + 255) / 256, 256, 0, stream>>>(
                gates, c_s, h_s, hs_hi, hs_lo);
            gemmP(hs_hi, hs_lo, probs_hi, probs_lo, H_,
                  nullptr, nullptr, nullptr, nullptr, 0,
                  probs_b, nullptr, logits, B_, V_);
            row_argmax_lse<<<B_, 256, 0, stream>>>(logits, msg + (size_t)t * B_, lp,
                                                   (t == L_ - 1) ? 1 : 0);
            if (t < L_ - 1)
                gather_emb_planes<<<B_, 64, 0, stream>>>(emb_s, msg + (size_t)t * B_,
                                                         we_hi, we_lo);
        }

        // ---- Receiver ----
        zero_f32<<<(B_ * H_ + 255) / 256, 256, 0, stream>>>(h_r, B_ * H_);
        zero_f32<<<(B_ * H_ + 255) / 256, 256, 0, stream>>>(c_r, B_ * H_);
        zero_f32<<<(B_ * H_ / 2 + 255) / 256, 256, 0, stream>>>(
            ws + OFF_HRP_HI, B_ * H_ / 2);
        zero_f32<<<(B_ * H_ / 2 + 255) / 256, 256, 0, stream>>>(
            ws + OFF_HRP_LO, B_ * H_ / 2);
        for (int t = 0; t < L_; ++t) {
            gather_emb_planes<<<B_, 64, 0, stream>>>(emb_r, msg + (size_t)t * B_,
                                                     we_hi, we_lo);
            gemmP(we_hi, we_lo, wihr_hi, wihr_lo, E_,
                  hr_hi, hr_lo, whhr_hi, whhr_lo, H_,
                  bih_r, bhh_r, gates, B_, 4 * H_);
            lstm_pointwise<<<(B_ * H_ + 255) / 256, 256, 0, stream>>>(
                gates, c_r, h_r, hr_hi, hr_lo);
        }
    } else {
        // ---- fallback: proven fp32-split path (ws too small for planes)
        gemm(target, aff_s_W, F_, nullptr, nullptr, 0, aff_s_b, nullptr, h_s, B_, H_);
        zero_f32<<<(B_ * H_ + 255) / 256, 256, 0, stream>>>(c_s, B_ * H_);
        broadcast_emb<<<B_, 128, 0, stream>>>(emb_s, start_tok, w_e);

        for (int t = 0; t < L_; ++t) {
            gemm(w_e, Wih_s, E_, h_s, Whh_s, H_, bih_s, bhh_s, gates, B_, 4 * H_);
            lstm_pointwise<<<(B_ * H_ + 255) / 256, 256, 0, stream>>>(
                gates, c_s, h_s, nullptr, nullptr);
            gemm(h_s, probs_W, H_, nullptr, nullptr, 0, probs_b, nullptr,
                 logits, B_, V_);
            row_argmax_lse<<<B_, 256, 0, stream>>>(logits, msg + (size_t)t * B_, lp,
                                                   (t == L_ - 1) ? 1 : 0);
            if (t < L_ - 1)
                gather_emb<<<B_, 128, 0, stream>>>(emb_s, msg + (size_t)t * B_, w_e);
        }

        zero_f32<<<(B_ * H_ + 255) / 256, 256, 0, stream>>>(h_r, B_ * H_);
        zero_f32<<<(B_ * H_ + 255) / 256, 256, 0, stream>>>(c_r, B_ * H_);
        for (int t = 0; t < L_; ++t) {
            gather_emb<<<B_, 128, 0, stream>>>(emb_r, msg + (size_t)t * B_, w_e);
            gemm(w_e, Wih_r, E_, h_r, Whh_r, H_, bih_r, bhh_r, gates, B_, 4 * H_);
            lstm_pointwise<<<(B_ * H_ + 255) / 256, 256, 0, stream>>>(
                gates, c_r, h_r, nullptr, nullptr);
        }
    }

    // ---- tail (common): r, scores, loss ----
    gemm(h_r, aff_r_W, H_, nullptr, nullptr, 0, aff_r_b, nullptr, r_buf, B_, F_);
    gemm(target, r_buf, F_, nullptr, nullptr, 0, nullptr, nullptr, sc, B_, B_);
    gemm(distract, r_buf, F_, nullptr, nullptr, 0, nullptr, nullptr,
         sc + (size_t)B_ * B_, D_ * B_, B_);

    loss_rows<<<B_, 256, 0, stream>>>(sc, lp, lossp, accf);
    finalize_k<<<1, 256, 0, stream>>>(lossp, accf, (float*)d_out);
}

// Round 5
// 6215.669 us; speedup vs baseline: 1.3238x; 1.0808x over previous
//
#include <hip/hip_runtime.h>
#include <cmath>

// Problem constants (fixed by the reference file)
#define B_ 1024
#define F_ 4096
#define V_ 20000
#define E_ 512
#define H_ 1024
#define L_ 20
#define D_ 4

typedef __bf16 bf16x8 __attribute__((ext_vector_type(8)));
typedef float  f32x4  __attribute__((ext_vector_type(4)));

#define BM 128
#define BN 128
#define BK 32

// padded row count for probs planes so loads need no guard (157*128)
#define VPAD 20096

// ---------------------------------------------------------------------------
// async global->LDS, 16B per lane. LDS dest is wave-uniform base + lane*16:
// our linear [rows][32]bf16 layout with thread t -> byte t*16 satisfies that.
// ---------------------------------------------------------------------------
__device__ __forceinline__ void gld_lds16(const void* g, void* l)
{
    __builtin_amdgcn_global_load_lds(
        (const __attribute__((address_space(1))) void*)g,
        (__attribute__((address_space(3))) void*)l, 16, 0, 0);
}

// ---------------------------------------------------------------------------
// OLD proven kernel: fp32 inputs, in-staging bf16 hi/lo split, 3 MFMAs/chunk.
// Kept only for the ws_size fallback paths.
// ---------------------------------------------------------------------------
__global__ __launch_bounds__(256, 2) void gemm_nt_split(
    const float* __restrict__ A1, const float* __restrict__ W1, int K1,
    const float* __restrict__ A2, const float* __restrict__ W2, int K2,
    const float* __restrict__ b1, const float* __restrict__ b2,
    float* __restrict__ C, int M, int N)
{
    __shared__ __align__(16) __bf16 As_hi[BM][BK];
    __shared__ __align__(16) __bf16 As_lo[BM][BK];
    __shared__ __align__(16) __bf16 Ws_hi[BN][BK];
    __shared__ __align__(16) __bf16 Ws_lo[BN][BK];

    const int tid  = threadIdx.x;
    const int bm   = blockIdx.y * BM;
    const int bn   = blockIdx.x * BN;
    const int srow = tid >> 1;
    const int scol = (tid & 1) * 16;
    const int lane = tid & 63;
    const int wv   = tid >> 6;
    const int wm   = (wv & 1) * 64;
    const int wn   = (wv >> 1) * 64;
    const int fm   = lane & 15;
    const int fq   = lane >> 4;

    const bool wok = (bn + srow) < N;

    f32x4 acc[4][4];
#pragma unroll
    for (int i = 0; i < 4; ++i)
#pragma unroll
        for (int j = 0; j < 4; ++j) acc[i][j] = (f32x4){0.f, 0.f, 0.f, 0.f};

#pragma unroll 1
    for (int s = 0; s < 2; ++s) {
        const float* A = s ? A2 : A1;
        const float* W = s ? W2 : W1;
        const int    K = s ? K2 : K1;
        if (!A) continue;
        const float* Arow = A + (size_t)(bm + srow) * K;
        const float* Wrow = W + (size_t)(bn + srow) * K;

        for (int k0 = 0; k0 < K; k0 += BK) {
            float av[16], wvv[16];
            const float* ap = Arow + k0 + scol;
            *(float4*)&av[0]   = *(const float4*)(ap + 0);
            *(float4*)&av[4]   = *(const float4*)(ap + 4);
            *(float4*)&av[8]   = *(const float4*)(ap + 8);
            *(float4*)&av[12]  = *(const float4*)(ap + 12);
            if (wok) {
                const float* wp = Wrow + k0 + scol;
                *(float4*)&wvv[0]  = *(const float4*)(wp + 0);
                *(float4*)&wvv[4]  = *(const float4*)(wp + 4);
                *(float4*)&wvv[8]  = *(const float4*)(wp + 8);
                *(float4*)&wvv[12] = *(const float4*)(wp + 12);
            } else {
#pragma unroll
                for (int v = 0; v < 16; ++v) wvv[v] = 0.f;
            }
            __syncthreads();

#pragma unroll
            for (int u = 0; u < 16; u += 8) {
                bf16x8 hh, ll;
#pragma unroll
                for (int v = 0; v < 8; ++v) {
                    float x = av[u + v];
                    __bf16 h = (__bf16)x;
                    hh[v] = h;
                    ll[v] = (__bf16)(x - (float)h);
                }
                *(bf16x8*)&As_hi[srow][scol + u] = hh;
                *(bf16x8*)&As_lo[srow][scol + u] = ll;
            }
#pragma unroll
            for (int u = 0; u < 16; u += 8) {
                bf16x8 hh, ll;
#pragma unroll
                for (int v = 0; v < 8; ++v) {
                    float x = wvv[u + v];
                    __bf16 h = (__bf16)x;
                    hh[v] = h;
                    ll[v] = (__bf16)(x - (float)h);
                }
                *(bf16x8*)&Ws_hi[srow][scol + u] = hh;
                *(bf16x8*)&Ws_lo[srow][scol + u] = ll;
            }
            __syncthreads();

            bf16x8 ah[4], al[4];
#pragma unroll
            for (int i = 0; i < 4; ++i) {
                ah[i] = *(const bf16x8*)&As_hi[wm + i * 16 + fm][fq * 8];
                al[i] = *(const bf16x8*)&As_lo[wm + i * 16 + fm][fq * 8];
            }
#pragma unroll
            for (int j = 0; j < 4; ++j) {
                bf16x8 bh = *(const bf16x8*)&Ws_hi[wn + j * 16 + fm][fq * 8];
                bf16x8 bl = *(const bf16x8*)&Ws_lo[wn + j * 16 + fm][fq * 8];
#pragma unroll
                for (int i = 0; i < 4; ++i) {
                    acc[i][j] = __builtin_amdgcn_mfma_f32_16x16x32_bf16(
                        al[i], bh, acc[i][j], 0, 0, 0);
                    acc[i][j] = __builtin_amdgcn_mfma_f32_16x16x32_bf16(
                        ah[i], bl, acc[i][j], 0, 0, 0);
                    acc[i][j] = __builtin_amdgcn_mfma_f32_16x16x32_bf16(
                        ah[i], bh, acc[i][j], 0, 0, 0);
                }
            }
        }
    }

#pragma unroll
    for (int j = 0; j < 4; ++j) {
        int col = bn + wn + j * 16 + fm;
        if (col >= N) continue;
        float badd = (b1 ? b1[col] : 0.f) + (b2 ? b2[col] : 0.f);
#pragma unroll
        for (int i = 0; i < 4; ++i) {
            int row0 = bm + wm + i * 16 + fq * 4;
            f32x4 v = acc[i][j];
#pragma unroll
            for (int r = 0; r < 4; ++r)
                C[(size_t)(row0 + r) * N + col] = v[r] + badd;
        }
    }
}

// ---------------------------------------------------------------------------
// Templated plane GEMM (TBM x TBN tile, BK=32, 256 threads, 2x2 waves).
// A/W pre-split into persistent bf16 hi/lo planes; global_load_lds staging.
// W planes row-padded to a multiple of TBN (no load guard; pad rows only
// reach store-guarded C columns). 3-MFMA split, same chunk order as
// gemm_nt_split -> bit-identical results.
// <128,128>: 4-5 blocks/CU grids (logits). <128,64>: doubles grid for the
// grid-starved 256-block GEMMs (gates, tail) -> 2 blocks/CU latency hiding.
// ---------------------------------------------------------------------------
template<int TBM, int TBN>
__global__ __launch_bounds__(256, 3) void gemm_nt_planes_t(
    const __bf16* __restrict__ Ah1, const __bf16* __restrict__ Al1,
    const __bf16* __restrict__ Wh1, const __bf16* __restrict__ Wl1, int K1,
    const __bf16* __restrict__ Ah2, const __bf16* __restrict__ Al2,
    const __bf16* __restrict__ Wh2, const __bf16* __restrict__ Wl2, int K2,
    const float* __restrict__ b1, const float* __restrict__ b2,
    float* __restrict__ C, int M, int N)
{
    constexpr int MI = TBM / 32;   // 16-row fragments per wave (M)
    constexpr int NJ = TBN / 32;   // 16-col fragments per wave (N)

    __shared__ __align__(16) __bf16 As_hi[TBM][BK];
    __shared__ __align__(16) __bf16 As_lo[TBM][BK];
    __shared__ __align__(16) __bf16 Ws_hi[TBN][BK];
    __shared__ __align__(16) __bf16 Ws_lo[TBN][BK];

    const int tid  = threadIdx.x;
    // bijective XCD-chunked, M-major remap (m204)
    const int nbx  = gridDim.x;
    const int nby  = gridDim.y;
    const int nwg  = nbx * nby;
    const int flat = blockIdx.y * nbx + blockIdx.x;
    const int q = nwg >> 3, r = nwg & 7;
    const int xcd = flat & 7, lead = flat >> 3;
    const int wgid = (xcd < r ? xcd * (q + 1) : r * (q + 1) + (xcd - r) * q) + lead;
    const int bm = (wgid % nby) * TBM;
    const int bn = (wgid / nby) * TBN;

    // staging: thread t -> row t>>2 (0..63), 8-elem col slot; LDS byte = t*16
    const int srow = tid >> 2;
    const int scol = (tid & 3) * 8;
    const int lane = tid & 63;
    const int wv   = tid >> 6;
    const int wm   = (wv & 1) * (TBM / 2);
    const int wn   = (wv >> 1) * (TBN / 2);
    const int fm   = lane & 15;
    const int fq   = lane >> 4;

    f32x4 acc[MI][NJ];
#pragma unroll
    for (int i = 0; i < MI; ++i)
#pragma unroll
        for (int j = 0; j < NJ; ++j) acc[i][j] = (f32x4){0.f, 0.f, 0.f, 0.f};

#pragma unroll 1
    for (int s = 0; s < 2; ++s) {
        const __bf16* Ah = s ? Ah2 : Ah1;
        const __bf16* Al = s ? Al2 : Al1;
        const __bf16* Wh = s ? Wh2 : Wh1;
        const __bf16* Wl = s ? Wl2 : Wl1;
        const int     K  = s ? K2  : K1;
        if (!Ah) continue;
        const size_t aoff = (size_t)(bm + srow) * K + scol;
        const size_t woff = (size_t)(bn + srow) * K + scol;

        for (int k0 = 0; k0 < K; k0 += BK) {
            __syncthreads();   // all waves done reading previous chunk
#pragma unroll
            for (int u = 0; u < TBM; u += 64) {
                gld_lds16(Ah + aoff + k0 + (size_t)u * K, &As_hi[srow + u][scol]);
                gld_lds16(Al + aoff + k0 + (size_t)u * K, &As_lo[srow + u][scol]);
            }
#pragma unroll
            for (int u = 0; u < TBN; u += 64) {
                gld_lds16(Wh + woff + k0 + (size_t)u * K, &Ws_hi[srow + u][scol]);
                gld_lds16(Wl + woff + k0 + (size_t)u * K, &Ws_lo[srow + u][scol]);
            }
            __syncthreads();   // compiler drains vmcnt(0) before s_barrier

            bf16x8 ah[MI], al[MI];
#pragma unroll
            for (int i = 0; i < MI; ++i) {
                ah[i] = *(const bf16x8*)&As_hi[wm + i * 16 + fm][fq * 8];
                al[i] = *(const bf16x8*)&As_lo[wm + i * 16 + fm][fq * 8];
            }
#pragma unroll
            for (int j = 0; j < NJ; ++j) {
                bf16x8 bh = *(const bf16x8*)&Ws_hi[wn + j * 16 + fm][fq * 8];
                bf16x8 bl = *(const bf16x8*)&Ws_lo[wn + j * 16 + fm][fq * 8];
#pragma unroll
                for (int i = 0; i < MI; ++i) {
                    acc[i][j] = __builtin_amdgcn_mfma_f32_16x16x32_bf16(
                        al[i], bh, acc[i][j], 0, 0, 0);
                    acc[i][j] = __builtin_amdgcn_mfma_f32_16x16x32_bf16(
                        ah[i], bl, acc[i][j], 0, 0, 0);
                    acc[i][j] = __builtin_amdgcn_mfma_f32_16x16x32_bf16(
                        ah[i], bh, acc[i][j], 0, 0, 0);
                }
            }
        }
    }

#pragma unroll
    for (int j = 0; j < NJ; ++j) {
        int col = bn + wn + j * 16 + fm;
        if (col >= N) continue;
        float badd = (b1 ? b1[col] : 0.f) + (b2 ? b2[col] : 0.f);
#pragma unroll
        for (int i = 0; i < MI; ++i) {
            int row0 = bm + wm + i * 16 + fq * 4;
            f32x4 v = acc[i][j];
#pragma unroll
            for (int rr = 0; rr < 4; ++rr)
                C[(size_t)(row0 + rr) * N + col] = v[rr] + badd;
        }
    }
}

// ---------------------------------------------------------------------------
// fp32 -> bf16 hi/lo plane split, 8 elems/thread
// ---------------------------------------------------------------------------
__global__ __launch_bounds__(256) void split_planes(
    const float* __restrict__ src, __bf16* __restrict__ hi,
    __bf16* __restrict__ lo, long n8)
{
    long i = (long)blockIdx.x * 256 + threadIdx.x;
    if (i >= n8) return;
    float4 a = ((const float4*)src)[2 * i];
    float4 b = ((const float4*)src)[2 * i + 1];
    float v[8] = {a.x, a.y, a.z, a.w, b.x, b.y, b.z, b.w};
    bf16x8 hh, ll;
#pragma unroll
    for (int j = 0; j < 8; ++j) {
        float x = v[j];
        __bf16 h = (__bf16)x;
        hh[j] = h;
        ll[j] = (__bf16)(x - (float)h);
    }
    ((bf16x8*)hi)[i] = hh;
    ((bf16x8*)lo)[i] = ll;
}

// ---------------------------------------------------------------------------
// LSTM pointwise; optionally emits h as bf16 hi/lo planes (free conversion)
// ---------------------------------------------------------------------------
__global__ __launch_bounds__(256) void lstm_pointwise(
    const float* __restrict__ gates, float* __restrict__ c, float* __restrict__ h,
    __bf16* __restrict__ hhi, __bf16* __restrict__ hlo)
{
    int i = blockIdx.x * blockDim.x + threadIdx.x;
    if (i >= B_ * H_) return;
    int b = i / H_, k = i % H_;
    const float* g = gates + (size_t)b * 4 * H_;
    float gi = g[k], gf = g[H_ + k], gg = g[2 * H_ + k], go = g[3 * H_ + k];
    float si = 1.f / (1.f + expf(-gi));
    float sf = 1.f / (1.f + expf(-gf));
    float so = 1.f / (1.f + expf(-go));
    float cn = sf * c[i] + si * tanhf(gg);
    c[i] = cn;
    float hv = so * tanhf(cn);
    h[i] = hv;
    if (hhi) {
        __bf16 hh = (__bf16)hv;
        hhi[i] = hh;
        hlo[i] = (__bf16)(hv - (float)hh);
    }
}

// ---------------------------------------------------------------------------
// Per-row argmax (first-occurrence) + online logsumexp. float4 loads (G13).
// ---------------------------------------------------------------------------
__global__ __launch_bounds__(256) void row_argmax_lse(
    const float* __restrict__ logits, int* __restrict__ tok,
    float* __restrict__ lp, int need_lp)
{
    int b = blockIdx.x;
    const float4* row4 = (const float4*)(logits + (size_t)b * V_);
    int tid = threadIdx.x;
    float m = -INFINITY; int mi = 0;
    float lm = -INFINITY, ls = 0.f;
    for (int j4 = tid; j4 < V_ / 4; j4 += 256) {
        float4 q = row4[j4];
        float vv[4] = {q.x, q.y, q.z, q.w};
#pragma unroll
        for (int u = 0; u < 4; ++u) {
            float v = vv[u];
            if (v > m) { m = v; mi = j4 * 4 + u; }
            if (need_lp) {
                if (v > lm) { ls = ls * expf(lm - v) + 1.f; lm = v; }
                else ls += expf(v - lm);
            }
        }
    }
    __shared__ float sm[256]; __shared__ int si[256];
    __shared__ float slm[256], sls[256];
    sm[tid] = m; si[tid] = mi; slm[tid] = lm; sls[tid] = ls;
    __syncthreads();
    for (int s = 128; s > 0; s >>= 1) {
        if (tid < s) {
            float vm = sm[tid + s]; int vi = si[tid + s];
            if (vm > sm[tid] || (vm == sm[tid] && vi < si[tid])) {
                sm[tid] = vm; si[tid] = vi;
            }
            if (need_lp) {
                float am = slm[tid], as = sls[tid];
                float bm2 = slm[tid + s], bs = sls[tid + s];
                if (am >= bm2) {
                    sls[tid] = as + bs * expf(bm2 - am);
                } else {
                    sls[tid] = bs + as * expf(am - bm2);
                    slm[tid] = bm2;
                }
            }
        }
        __syncthreads();
    }
    if (tid == 0) {
        tok[b] = si[0];
        if (need_lp) lp[b] = sm[0] - (slm[0] + logf(sls[0]));
    }
}

// ---------------------------------------------------------------------------
// Embedding gathers (fp32 versions for fallback; plane versions for fast path)
// ---------------------------------------------------------------------------
__global__ __launch_bounds__(128) void gather_emb(
    const float* __restrict__ emb, const int* __restrict__ tok,
    float* __restrict__ out)
{
    int b = blockIdx.x;
    int t = tok[b];
    const float4* src = (const float4*)(emb + (size_t)t * E_);
    float4* dst = (float4*)(out + (size_t)b * E_);
    for (int e = threadIdx.x; e < E_ / 4; e += blockDim.x) dst[e] = src[e];
}

__global__ __launch_bounds__(128) void broadcast_emb(
    const float* __restrict__ emb, const int* __restrict__ sidx,
    float* __restrict__ out)
{
    int b = blockIdx.x;
    int t = sidx[0];
    const float4* src = (const float4*)(emb + (size_t)t * E_);
    float4* dst = (float4*)(out + (size_t)b * E_);
    for (int e = threadIdx.x; e < E_ / 4; e += blockDim.x) dst[e] = src[e];
}

__device__ __forceinline__ void emb_row_split(
    const float* __restrict__ emb, int t, int b, int i,
    __bf16* __restrict__ whi, __bf16* __restrict__ wlo)
{
    const float4* src = (const float4*)(emb + (size_t)t * E_);
    float4 a = src[2 * i], c2 = src[2 * i + 1];
    float v[8] = {a.x, a.y, a.z, a.w, c2.x, c2.y, c2.z, c2.w};
    bf16x8 hh, ll;
#pragma unroll
    for (int j = 0; j < 8; ++j) {
        float x = v[j];
        __bf16 h = (__bf16)x;
        hh[j] = h;
        ll[j] = (__bf16)(x - (float)h);
    }
    ((bf16x8*)(whi + (size_t)b * E_))[i] = hh;
    ((bf16x8*)(wlo + (size_t)b * E_))[i] = ll;
}

__global__ __launch_bounds__(64) void gather_emb_planes(
    const float* __restrict__ emb, const int* __restrict__ tok,
    __bf16* __restrict__ whi, __bf16* __restrict__ wlo)
{
    emb_row_split(emb, tok[blockIdx.x], blockIdx.x, threadIdx.x, whi, wlo);
}

__global__ __launch_bounds__(64) void broadcast_emb_planes(
    const float* __restrict__ emb, const int* __restrict__ sidx,
    __bf16* __restrict__ whi, __bf16* __restrict__ wlo)
{
    emb_row_split(emb, sidx[0], blockIdx.x, threadIdx.x, whi, wlo);
}

__global__ __launch_bounds__(256) void zero_f32(float* __restrict__ p, int n)
{
    int i = blockIdx.x * blockDim.x + threadIdx.x;
    if (i < n) p[i] = 0.f;
}

// ---------------------------------------------------------------------------
// Loss rows + finalize (unchanged)
// ---------------------------------------------------------------------------
__global__ __launch_bounds__(256) void loss_rows(
    const float* __restrict__ sc, const float* __restrict__ lp,
    float* __restrict__ loss_part, float* __restrict__ acc_flag)
{
    int i = blockIdx.x; int tid = threadIdx.x;
    const float* tsrow = sc + (size_t)i * B_;
    float lsum = 0.f, tps = 0.f;
    float dps[4] = {0.f, 0.f, 0.f, 0.f};
    for (int j = tid; j < B_; j += 256) {
        float tsv = tsrow[j];
        float hv = 0.f;
#pragma unroll
        for (int d = 0; d < 4; ++d) {
            float dv = sc[((size_t)(1 + d) * B_ + i) * B_ + j];
            float t = 1.f - tsv + dv;
            hv += (t > 0.f) ? t : 0.f;
            dps[d] += expf(dv);
        }
        lsum += hv * lp[j];
        tps += expf(tsv);
    }
    __shared__ float red[6][256];
    red[0][tid] = lsum; red[1][tid] = tps;
    red[2][tid] = dps[0]; red[3][tid] = dps[1];
    red[4][tid] = dps[2]; red[5][tid] = dps[3];
    __syncthreads();
    for (int s = 128; s > 0; s >>= 1) {
        if (tid < s) {
#pragma unroll
            for (int q = 0; q < 6; ++q) red[q][tid] += red[q][tid + s];
        }
        __syncthreads();
    }
    if (tid == 0) {
        loss_part[i] = -red[0][0];
        float tp = red[1][0];
        float mx = fmaxf(fmaxf(red[2][0], red[3][0]), fmaxf(red[4][0], red[5][0]));
        acc_flag[i] = (tp >= mx) ? 1.f : 0.f;
    }
}

__global__ __launch_bounds__(256) void finalize_k(
    const float* __restrict__ loss_part, const float* __restrict__ acc_flag,
    float* __restrict__ out)
{
    int tid = threadIdx.x;
    float ls = 0.f, ac = 0.f;
    for (int i = tid; i < B_; i += 256) { ls += loss_part[i]; ac += acc_flag[i]; }
    __shared__ float s1[256], s2[256];
    s1[tid] = ls; s2[tid] = ac;
    __syncthreads();
    for (int s = 128; s > 0; s >>= 1) {
        if (tid < s) { s1[tid] += s1[tid + s]; s2[tid] += s2[tid + s]; }
        __syncthreads();
    }
    if (tid == 0) {
        out[0] = s1[0] / ((float)B_ * (float)B_);
        out[1] = s2[0] / (float)B_;
    }
}

// ---------------------------------------------------------------------------
// Host launcher
// ---------------------------------------------------------------------------
extern "C" void kernel_launch(void* const* d_in, const int* in_sizes, int n_in,
                              void* d_out, int out_size, void* d_ws, size_t ws_size,
                              hipStream_t stream)
{
    const float* target    = (const float*)d_in[0];
    const float* distract  = (const float*)d_in[1];
    const int*   start_tok = (const int*)d_in[2];
    const float* emb_s   = (const float*)d_in[4];
    const float* Wih_s   = (const float*)d_in[5];
    const float* Whh_s   = (const float*)d_in[6];
    const float* bih_s   = (const float*)d_in[7];
    const float* bhh_s   = (const float*)d_in[8];
    const float* aff_s_W = (const float*)d_in[9];
    const float* aff_s_b = (const float*)d_in[10];
    const float* probs_W = (const float*)d_in[11];
    const float* probs_b = (const float*)d_in[12];
    const float* emb_r   = (const float*)d_in[13];
    const float* Wih_r   = (const float*)d_in[14];
    const float* Whh_r   = (const float*)d_in[15];
    const float* bih_r   = (const float*)d_in[16];
    const float* bhh_r   = (const float*)d_in[17];
    const float* aff_r_W = (const float*)d_in[18];
    const float* aff_r_b = (const float*)d_in[19];

    float* ws = (float*)d_ws;
    // ---- base layout (identical to proven baseline)
    const size_t OFF_HS     = 0;
    const size_t OFF_CS     = 1048576;
    const size_t OFF_WE     = 2097152;
    const size_t OFF_GATES  = 2621440;
    const size_t OFF_HR     = 6815744;
    const size_t OFF_CR     = 7864320;
    const size_t OFF_LP     = 8912896;
    const size_t OFF_LOSSP  = 8916992;
    const size_t OFF_ACCF   = 8921088;
    const size_t OFF_MSG    = 8925184;
    const size_t OFF_LOGITS = 9437184;
    const size_t OFF_R      = 9437184;
    const size_t OFF_SC     = 13631488;
    // ---- bf16 plane region, LSTM loop (float offsets; plane = elems/2 floats)
    const size_t OFF_PROBS_HI = 29917184;  // [VPAD,H] bf16
    const size_t OFF_PROBS_LO = 40206336;
    const size_t OFF_WIHS_HI  = 50495488;  // [4H,E]
    const size_t OFF_WIHS_LO  = 51544064;
    const size_t OFF_WHHS_HI  = 52592640;  // [4H,H]
    const size_t OFF_WHHS_LO  = 54689792;
    const size_t OFF_WIHR_HI  = 56786944;
    const size_t OFF_WIHR_LO  = 57835520;
    const size_t OFF_WHHR_HI  = 58884096;
    const size_t OFF_WHHR_LO  = 60981248;
    const size_t OFF_WEP_HI   = 63078400;  // [B,E]
    const size_t OFF_WEP_LO   = 63340544;
    const size_t OFF_HSP_HI   = 63602688;  // [B,H]
    const size_t OFF_HSP_LO   = 64126976;
    const size_t OFF_HRP_HI   = 64651264;  // [B,H]
    const size_t OFF_HRP_LO   = 65175552;
    const size_t TOTAL_FLOATS = 65699840;  // 262.8 MB
    // ---- bf16 plane region, tail (appended; gated by ws_size)
    const size_t OFF_AFFS_HI = 65699840;   // [H,F]
    const size_t OFF_AFFS_LO = 67796992;
    const size_t OFF_AFFR_HI = 69894144;   // [F,H]
    const size_t OFF_AFFR_LO = 71991296;
    const size_t OFF_RP_HI   = 74088448;   // [B,F]
    const size_t OFF_RP_LO   = 76185600;
    const size_t OFF_TD_HI   = 78282752;   // [5B,F] target rows 0..B-1, distract after
    const size_t OFF_TD_LO   = 88768512;
    const size_t TOTAL2_FLOATS = 99254272; // 397.0 MB

    float* h_s    = ws + OFF_HS;
    float* c_s    = ws + OFF_CS;
    float* w_e    = ws + OFF_WE;
    float* gates  = ws + OFF_GATES;
    float* h_r    = ws + OFF_HR;
    float* c_r    = ws + OFF_CR;
    float* lp     = ws + OFF_LP;
    float* lossp  = ws + OFF_LOSSP;
    float* accf   = ws + OFF_ACCF;
    int*   msg    = (int*)(ws + OFF_MSG);
    float* logits = ws + OFF_LOGITS;
    float* r_buf  = ws + OFF_R;
    float* sc     = ws + OFF_SC;

    auto gemm = [&](const float* A1, const float* W1, int K1,
                    const float* A2, const float* W2, int K2,
                    const float* b1, const float* b2,
                    float* C, int M, int N) {
        dim3 grid((N + BN - 1) / BN, M / BM);
        gemm_nt_split<<<grid, dim3(256), 0, stream>>>(A1, W1, K1, A2, W2, K2,
                                                      b1, b2, C, M, N);
    };

    const bool fast      = ws_size >= TOTAL_FLOATS * sizeof(float);
    const bool fast_tail = ws_size >= TOTAL2_FLOATS * sizeof(float);

    if (fast) {
        __bf16* probs_hi = (__bf16*)(ws + OFF_PROBS_HI);
        __bf16* probs_lo = (__bf16*)(ws + OFF_PROBS_LO);
        __bf16* wihs_hi  = (__bf16*)(ws + OFF_WIHS_HI);
        __bf16* wihs_lo  = (__bf16*)(ws + OFF_WIHS_LO);
        __bf16* whhs_hi  = (__bf16*)(ws + OFF_WHHS_HI);
        __bf16* whhs_lo  = (__bf16*)(ws + OFF_WHHS_LO);
        __bf16* wihr_hi  = (__bf16*)(ws + OFF_WIHR_HI);
        __bf16* wihr_lo  = (__bf16*)(ws + OFF_WIHR_LO);
        __bf16* whhr_hi  = (__bf16*)(ws + OFF_WHHR_HI);
        __bf16* whhr_lo  = (__bf16*)(ws + OFF_WHHR_LO);
        __bf16* we_hi    = (__bf16*)(ws + OFF_WEP_HI);
        __bf16* we_lo    = (__bf16*)(ws + OFF_WEP_LO);
        __bf16* hs_hi    = (__bf16*)(ws + OFF_HSP_HI);
        __bf16* hs_lo    = (__bf16*)(ws + OFF_HSP_LO);
        __bf16* hr_hi    = (__bf16*)(ws + OFF_HRP_HI);
        __bf16* hr_lo    = (__bf16*)(ws + OFF_HRP_LO);
        __bf16* affs_hi  = (__bf16*)(ws + OFF_AFFS_HI);
        __bf16* affs_lo  = (__bf16*)(ws + OFF_AFFS_LO);
        __bf16* affr_hi  = (__bf16*)(ws + OFF_AFFR_HI);
        __bf16* affr_lo  = (__bf16*)(ws + OFF_AFFR_LO);
        __bf16* rp_hi    = (__bf16*)(ws + OFF_RP_HI);
        __bf16* rp_lo    = (__bf16*)(ws + OFF_RP_LO);
        __bf16* td_hi    = (__bf16*)(ws + OFF_TD_HI);
        __bf16* td_lo    = (__bf16*)(ws + OFF_TD_LO);

        auto cvt = [&](const float* src, __bf16* hi, __bf16* lo, long n) {
            long n8 = n / 8;
            split_planes<<<(unsigned)((n8 + 255) / 256), 256, 0, stream>>>(
                src, hi, lo, n8);
        };
        auto gemmP = [&](const __bf16* Ah1, const __bf16* Al1,
                         const __bf16* Wh1, const __bf16* Wl1, int K1,
                         const __bf16* Ah2, const __bf16* Al2,
                         const __bf16* Wh2, const __bf16* Wl2, int K2,
                         const float* b1, const float* b2,
                         float* C, int M, int N) {
            dim3 grid((N + BN - 1) / BN, M / BM);
            gemm_nt_planes_t<128, 128><<<grid, dim3(256), 0, stream>>>(
                Ah1, Al1, Wh1, Wl1, K1, Ah2, Al2, Wh2, Wl2, K2, b1, b2, C, M, N);
        };
        auto gemmP64 = [&](const __bf16* Ah1, const __bf16* Al1,
                           const __bf16* Wh1, const __bf16* Wl1, int K1,
                           const __bf16* Ah2, const __bf16* Al2,
                           const __bf16* Wh2, const __bf16* Wl2, int K2,
                           const float* b1, const float* b2,
                           float* C, int M, int N) {
            dim3 grid((N + 63) / 64, M / BM);
            gemm_nt_planes_t<128, 64><<<grid, dim3(256), 0, stream>>>(
                Ah1, Al1, Wh1, Wl1, K1, Ah2, Al2, Wh2, Wl2, K2, b1, b2, C, M, N);
        };

        // ---- one-time weight plane conversions
        cvt(probs_W, probs_hi, probs_lo, (long)V_ * H_);
        cvt(Wih_s, wihs_hi, wihs_lo, (long)4 * H_ * E_);
        cvt(Whh_s, whhs_hi, whhs_lo, (long)4 * H_ * H_);
        cvt(Wih_r, wihr_hi, wihr_lo, (long)4 * H_ * E_);
        cvt(Whh_r, whhr_hi, whhr_lo, (long)4 * H_ * H_);
        // zero probs pad rows (20000..20095) for determinism
        {
            int padn = (VPAD - V_) * H_ / 2;  // floats
            zero_f32<<<(padn + 255) / 256, 256, 0, stream>>>(
                ws + OFF_PROBS_HI + (size_t)V_ * H_ / 2, padn);
            zero_f32<<<(padn + 255) / 256, 256, 0, stream>>>(
                ws + OFF_PROBS_LO + (size_t)V_ * H_ / 2, padn);
        }
        if (fast_tail) {
            cvt(aff_s_W, affs_hi, affs_lo, (long)H_ * F_);
            cvt(aff_r_W, affr_hi, affr_lo, (long)F_ * H_);
            cvt(target, td_hi, td_lo, (long)B_ * F_);
            cvt(distract, td_hi + (size_t)B_ * F_, td_lo + (size_t)B_ * F_,
                (long)D_ * B_ * F_);
        }

        // ---- Sender ----
        if (fast_tail)
            gemmP64(td_hi, td_lo, affs_hi, affs_lo, F_,
                    nullptr, nullptr, nullptr, nullptr, 0,
                    aff_s_b, nullptr, h_s, B_, H_);
        else
            gemm(target, aff_s_W, F_, nullptr, nullptr, 0, aff_s_b, nullptr,
                 h_s, B_, H_);
        cvt(h_s, hs_hi, hs_lo, (long)B_ * H_);
        zero_f32<<<(B_ * H_ + 255) / 256, 256, 0, stream>>>(c_s, B_ * H_);
        broadcast_emb_planes<<<B_, 64, 0, stream>>>(emb_s, start_tok, we_hi, we_lo);

        for (int t = 0; t < L_; ++t) {
            gemmP64(we_hi, we_lo, wihs_hi, wihs_lo, E_,
                    hs_hi, hs_lo, whhs_hi, whhs_lo, H_,
                    bih_s, bhh_s, gates, B_, 4 * H_);
            lstm_pointwise<<<(B_ * H_ + 255) / 256, 256, 0, stream>>>(
                gates, c_s, h_s, hs_hi, hs_lo);
            gemmP(hs_hi, hs_lo, probs_hi, probs_lo, H_,
                  nullptr, nullptr, nullptr, nullptr, 0,
                  probs_b, nullptr, logits, B_, V_);
            row_argmax_lse<<<B_, 256, 0, stream>>>(logits, msg + (size_t)t * B_, lp,
                                                   (t == L_ - 1) ? 1 : 0);
            if (t < L_ - 1)
                gather_emb_planes<<<B_, 64, 0, stream>>>(emb_s, msg + (size_t)t * B_,
                                                         we_hi, we_lo);
        }

        // ---- Receiver ----
        zero_f32<<<(B_ * H_ + 255) / 256, 256, 0, stream>>>(h_r, B_ * H_);
        zero_f32<<<(B_ * H_ + 255) / 256, 256, 0, stream>>>(c_r, B_ * H_);
        zero_f32<<<(B_ * H_ / 2 + 255) / 256, 256, 0, stream>>>(
            ws + OFF_HRP_HI, B_ * H_ / 2);
        zero_f32<<<(B_ * H_ / 2 + 255) / 256, 256, 0, stream>>>(
            ws + OFF_HRP_LO, B_ * H_ / 2);
        for (int t = 0; t < L_; ++t) {
            gather_emb_planes<<<B_, 64, 0, stream>>>(emb_r, msg + (size_t)t * B_,
                                                     we_hi, we_lo);
            gemmP64(we_hi, we_lo, wihr_hi, wihr_lo, E_,
                    hr_hi, hr_lo, whhr_hi, whhr_lo, H_,
                    bih_r, bhh_r, gates, B_, 4 * H_);
            lstm_pointwise<<<(B_ * H_ + 255) / 256, 256, 0, stream>>>(
                gates, c_r, h_r, hr_hi, hr_lo);
        }

        // ---- tail ----
        if (fast_tail) {
            // r = h_r @ aff_r_W.T + b (planes, 512 blocks)
            gemmP64(hr_hi, hr_lo, affr_hi, affr_lo, H_,
                    nullptr, nullptr, nullptr, nullptr, 0,
                    aff_r_b, nullptr, r_buf, B_, F_);
            cvt(r_buf, rp_hi, rp_lo, (long)B_ * F_);
            // fused [target; distract] @ r.T -> sc [5B, B] (640 blocks)
            gemmP64(td_hi, td_lo, rp_hi, rp_lo, F_,
                    nullptr, nullptr, nullptr, nullptr, 0,
                    nullptr, nullptr, sc, (1 + D_) * B_, B_);
        } else {
            gemm(h_r, aff_r_W, H_, nullptr, nullptr, 0, aff_r_b, nullptr,
                 r_buf, B_, F_);
            gemm(target, r_buf, F_, nullptr, nullptr, 0, nullptr, nullptr,
                 sc, B_, B_);
            gemm(distract, r_buf, F_, nullptr, nullptr, 0, nullptr, nullptr,
                 sc + (size_t)B_ * B_, D_ * B_, B_);
        }
    } else {
        // ---- fallback: proven fp32-split path (ws too small for planes)
        gemm(target, aff_s_W, F_, nullptr, nullptr, 0, aff_s_b, nullptr, h_s, B_, H_);
        zero_f32<<<(B_ * H_ + 255) / 256, 256, 0, stream>>>(c_s, B_ * H_);
        broadcast_emb<<<B_, 128, 0, stream>>>(emb_s, start_tok, w_e);

        for (int t = 0; t < L_; ++t) {
            gemm(w_e, Wih_s, E_, h_s, Whh_s, H_, bih_s, bhh_s, gates, B_, 4 * H_);
            lstm_pointwise<<<(B_ * H_ + 255) / 256, 256, 0, stream>>>(
                gates, c_s, h_s, nullptr, nullptr);
            gemm(h_s, probs_W, H_, nullptr, nullptr, 0, probs_b, nullptr,
                 logits, B_, V_);
            row_argmax_lse<<<B_, 256, 0, stream>>>(logits, msg + (size_t)t * B_, lp,
                                                   (t == L_ - 1) ? 1 : 0);
            if (t < L_ - 1)
                gather_emb<<<B_, 128, 0, stream>>>(emb_s, msg + (size_t)t * B_, w_e);
        }

        zero_f32<<<(B_ * H_ + 255) / 256, 256, 0, stream>>>(h_r, B_ * H_);
        zero_f32<<<(B_ * H_ + 255) / 256, 256, 0, stream>>>(c_r, B_ * H_);
        for (int t = 0; t < L_; ++t) {
            gather_emb<<<B_, 128, 0, stream>>>(emb_r, msg + (size_t)t * B_, w_e);
            gemm(w_e, Wih_r, E_, h_r, Whh_r, H_, bih_r, bhh_r, gates, B_, 4 * H_);
            lstm_pointwise<<<(B_ * H_ + 255) / 256, 256, 0, stream>>>(
                gates, c_r, h_r, nullptr, nullptr);
        }

        gemm(h_r, aff_r_W, H_, nullptr, nullptr, 0, aff_r_b, nullptr, r_buf, B_, F_);
        gemm(target, r_buf, F_, nullptr, nullptr, 0, nullptr, nullptr, sc, B_, B_);
        gemm(distract, r_buf, F_, nullptr, nullptr, 0, nullptr, nullptr,
             sc + (size_t)B_ * B_, D_ * B_, B_);
    }

    // ---- loss + accuracy (common) ----
    loss_rows<<<B_, 256, 0, stream>>>(sc, lp, lossp, accf);
    finalize_k<<<1, 256, 0, stream>>>(lossp, accf, (float*)d_out);
}

// Round 6
// 6008.272 us; speedup vs baseline: 1.3695x; 1.0345x over previous
//
#include <hip/hip_runtime.h>
#include <cmath>

// Problem constants (fixed by the reference file)
#define B_ 1024
#define F_ 4096
#define V_ 20000
#define E_ 512
#define H_ 1024
#define L_ 20
#define D_ 4

typedef __bf16 bf16x8 __attribute__((ext_vector_type(8)));
typedef float  f32x4  __attribute__((ext_vector_type(4)));

#define BM 128
#define BN 128
#define BK 32

// padded row count for probs planes so loads need no guard (157*128)
#define VPAD 20096

// ---------------------------------------------------------------------------
// async global->LDS, 16B per lane. LDS dest is wave-uniform base + lane*16:
// our linear [rows][32]bf16 layout with thread t -> byte t*16 satisfies that.
// ---------------------------------------------------------------------------
__device__ __forceinline__ void gld_lds16(const void* g, void* l)
{
    __builtin_amdgcn_global_load_lds(
        (const __attribute__((address_space(1))) void*)g,
        (__attribute__((address_space(3))) void*)l, 16, 0, 0);
}

// ---------------------------------------------------------------------------
// OLD proven kernel: fp32 inputs, in-staging bf16 hi/lo split, 3 MFMAs/chunk.
// Used for h0 (one-shot) and the ws_size fallback path.
// ---------------------------------------------------------------------------
__global__ __launch_bounds__(256, 2) void gemm_nt_split(
    const float* __restrict__ A1, const float* __restrict__ W1, int K1,
    const float* __restrict__ A2, const float* __restrict__ W2, int K2,
    const float* __restrict__ b1, const float* __restrict__ b2,
    float* __restrict__ C, int M, int N)
{
    __shared__ __align__(16) __bf16 As_hi[BM][BK];
    __shared__ __align__(16) __bf16 As_lo[BM][BK];
    __shared__ __align__(16) __bf16 Ws_hi[BN][BK];
    __shared__ __align__(16) __bf16 Ws_lo[BN][BK];

    const int tid  = threadIdx.x;
    const int bm   = blockIdx.y * BM;
    const int bn   = blockIdx.x * BN;
    const int srow = tid >> 1;
    const int scol = (tid & 1) * 16;
    const int lane = tid & 63;
    const int wv   = tid >> 6;
    const int wm   = (wv & 1) * 64;
    const int wn   = (wv >> 1) * 64;
    const int fm   = lane & 15;
    const int fq   = lane >> 4;

    const bool wok = (bn + srow) < N;

    f32x4 acc[4][4];
#pragma unroll
    for (int i = 0; i < 4; ++i)
#pragma unroll
        for (int j = 0; j < 4; ++j) acc[i][j] = (f32x4){0.f, 0.f, 0.f, 0.f};

#pragma unroll 1
    for (int s = 0; s < 2; ++s) {
        const float* A = s ? A2 : A1;
        const float* W = s ? W2 : W1;
        const int    K = s ? K2 : K1;
        if (!A) continue;
        const float* Arow = A + (size_t)(bm + srow) * K;
        const float* Wrow = W + (size_t)(bn + srow) * K;

        for (int k0 = 0; k0 < K; k0 += BK) {
            float av[16], wvv[16];
            const float* ap = Arow + k0 + scol;
            *(float4*)&av[0]   = *(const float4*)(ap + 0);
            *(float4*)&av[4]   = *(const float4*)(ap + 4);
            *(float4*)&av[8]   = *(const float4*)(ap + 8);
            *(float4*)&av[12]  = *(const float4*)(ap + 12);
            if (wok) {
                const float* wp = Wrow + k0 + scol;
                *(float4*)&wvv[0]  = *(const float4*)(wp + 0);
                *(float4*)&wvv[4]  = *(const float4*)(wp + 4);
                *(float4*)&wvv[8]  = *(const float4*)(wp + 8);
                *(float4*)&wvv[12] = *(const float4*)(wp + 12);
            } else {
#pragma unroll
                for (int v = 0; v < 16; ++v) wvv[v] = 0.f;
            }
            __syncthreads();

#pragma unroll
            for (int u = 0; u < 16; u += 8) {
                bf16x8 hh, ll;
#pragma unroll
                for (int v = 0; v < 8; ++v) {
                    float x = av[u + v];
                    __bf16 h = (__bf16)x;
                    hh[v] = h;
                    ll[v] = (__bf16)(x - (float)h);
                }
                *(bf16x8*)&As_hi[srow][scol + u] = hh;
                *(bf16x8*)&As_lo[srow][scol + u] = ll;
            }
#pragma unroll
            for (int u = 0; u < 16; u += 8) {
                bf16x8 hh, ll;
#pragma unroll
                for (int v = 0; v < 8; ++v) {
                    float x = wvv[u + v];
                    __bf16 h = (__bf16)x;
                    hh[v] = h;
                    ll[v] = (__bf16)(x - (float)h);
                }
                *(bf16x8*)&Ws_hi[srow][scol + u] = hh;
                *(bf16x8*)&Ws_lo[srow][scol + u] = ll;
            }
            __syncthreads();

            bf16x8 ah[4], al[4];
#pragma unroll
            for (int i = 0; i < 4; ++i) {
                ah[i] = *(const bf16x8*)&As_hi[wm + i * 16 + fm][fq * 8];
                al[i] = *(const bf16x8*)&As_lo[wm + i * 16 + fm][fq * 8];
            }
#pragma unroll
            for (int j = 0; j < 4; ++j) {
                bf16x8 bh = *(const bf16x8*)&Ws_hi[wn + j * 16 + fm][fq * 8];
                bf16x8 bl = *(const bf16x8*)&Ws_lo[wn + j * 16 + fm][fq * 8];
#pragma unroll
                for (int i = 0; i < 4; ++i) {
                    acc[i][j] = __builtin_amdgcn_mfma_f32_16x16x32_bf16(
                        al[i], bh, acc[i][j], 0, 0, 0);
                    acc[i][j] = __builtin_amdgcn_mfma_f32_16x16x32_bf16(
                        ah[i], bl, acc[i][j], 0, 0, 0);
                    acc[i][j] = __builtin_amdgcn_mfma_f32_16x16x32_bf16(
                        ah[i], bh, acc[i][j], 0, 0, 0);
                }
            }
        }
    }

#pragma unroll
    for (int j = 0; j < 4; ++j) {
        int col = bn + wn + j * 16 + fm;
        if (col >= N) continue;
        float badd = (b1 ? b1[col] : 0.f) + (b2 ? b2[col] : 0.f);
#pragma unroll
        for (int i = 0; i < 4; ++i) {
            int row0 = bm + wm + i * 16 + fq * 4;
            f32x4 v = acc[i][j];
#pragma unroll
            for (int r = 0; r < 4; ++r)
                C[(size_t)(row0 + r) * N + col] = v[r] + badd;
        }
    }
}

// ---------------------------------------------------------------------------
// Templated plane GEMM (TBM x TBN tile, BK=32, 256 threads, 2x2 waves).
// A/W pre-split into persistent bf16 hi/lo planes; global_load_lds staging.
// W planes row-padded to a multiple of TBN (no load guard; pad rows only
// reach store-guarded C columns). 3-MFMA split, same chunk order as
// gemm_nt_split -> bit-identical results.
// ---------------------------------------------------------------------------
template<int TBM, int TBN>
__global__ __launch_bounds__(256, 3) void gemm_nt_planes_t(
    const __bf16* __restrict__ Ah1, const __bf16* __restrict__ Al1,
    const __bf16* __restrict__ Wh1, const __bf16* __restrict__ Wl1, int K1,
    const __bf16* __restrict__ Ah2, const __bf16* __restrict__ Al2,
    const __bf16* __restrict__ Wh2, const __bf16* __restrict__ Wl2, int K2,
    const float* __restrict__ b1, const float* __restrict__ b2,
    float* __restrict__ C, int M, int N)
{
    constexpr int MI = TBM / 32;   // 16-row fragments per wave (M)
    constexpr int NJ = TBN / 32;   // 16-col fragments per wave (N)

    __shared__ __align__(16) __bf16 As_hi[TBM][BK];
    __shared__ __align__(16) __bf16 As_lo[TBM][BK];
    __shared__ __align__(16) __bf16 Ws_hi[TBN][BK];
    __shared__ __align__(16) __bf16 Ws_lo[TBN][BK];

    const int tid  = threadIdx.x;
    // bijective XCD-chunked, M-major remap (m204)
    const int nbx  = gridDim.x;
    const int nby  = gridDim.y;
    const int nwg  = nbx * nby;
    const int flat = blockIdx.y * nbx + blockIdx.x;
    const int q = nwg >> 3, r = nwg & 7;
    const int xcd = flat & 7, lead = flat >> 3;
    const int wgid = (xcd < r ? xcd * (q + 1) : r * (q + 1) + (xcd - r) * q) + lead;
    const int bm = (wgid % nby) * TBM;
    const int bn = (wgid / nby) * TBN;

    // staging: thread t -> row t>>2 (0..63), 8-elem col slot; LDS byte = t*16
    const int srow = tid >> 2;
    const int scol = (tid & 3) * 8;
    const int lane = tid & 63;
    const int wv   = tid >> 6;
    const int wm   = (wv & 1) * (TBM / 2);
    const int wn   = (wv >> 1) * (TBN / 2);
    const int fm   = lane & 15;
    const int fq   = lane >> 4;

    f32x4 acc[MI][NJ];
#pragma unroll
    for (int i = 0; i < MI; ++i)
#pragma unroll
        for (int j = 0; j < NJ; ++j) acc[i][j] = (f32x4){0.f, 0.f, 0.f, 0.f};

#pragma unroll 1
    for (int s = 0; s < 2; ++s) {
        const __bf16* Ah = s ? Ah2 : Ah1;
        const __bf16* Al = s ? Al2 : Al1;
        const __bf16* Wh = s ? Wh2 : Wh1;
        const __bf16* Wl = s ? Wl2 : Wl1;
        const int     K  = s ? K2  : K1;
        if (!Ah) continue;
        const size_t aoff = (size_t)(bm + srow) * K + scol;
        const size_t woff = (size_t)(bn + srow) * K + scol;

        for (int k0 = 0; k0 < K; k0 += BK) {
            __syncthreads();   // all waves done reading previous chunk
#pragma unroll
            for (int u = 0; u < TBM; u += 64) {
                gld_lds16(Ah + aoff + k0 + (size_t)u * K, &As_hi[srow + u][scol]);
                gld_lds16(Al + aoff + k0 + (size_t)u * K, &As_lo[srow + u][scol]);
            }
#pragma unroll
            for (int u = 0; u < TBN; u += 64) {
                gld_lds16(Wh + woff + k0 + (size_t)u * K, &Ws_hi[srow + u][scol]);
                gld_lds16(Wl + woff + k0 + (size_t)u * K, &Ws_lo[srow + u][scol]);
            }
            __syncthreads();   // compiler drains vmcnt(0) before s_barrier

            bf16x8 ah[MI], al[MI];
#pragma unroll
            for (int i = 0; i < MI; ++i) {
                ah[i] = *(const bf16x8*)&As_hi[wm + i * 16 + fm][fq * 8];
                al[i] = *(const bf16x8*)&As_lo[wm + i * 16 + fm][fq * 8];
            }
#pragma unroll
            for (int j = 0; j < NJ; ++j) {
                bf16x8 bh = *(const bf16x8*)&Ws_hi[wn + j * 16 + fm][fq * 8];
                bf16x8 bl = *(const bf16x8*)&Ws_lo[wn + j * 16 + fm][fq * 8];
#pragma unroll
                for (int i = 0; i < MI; ++i) {
                    acc[i][j] = __builtin_amdgcn_mfma_f32_16x16x32_bf16(
                        al[i], bh, acc[i][j], 0, 0, 0);
                    acc[i][j] = __builtin_amdgcn_mfma_f32_16x16x32_bf16(
                        ah[i], bl, acc[i][j], 0, 0, 0);
                    acc[i][j] = __builtin_amdgcn_mfma_f32_16x16x32_bf16(
                        ah[i], bh, acc[i][j], 0, 0, 0);
                }
            }
        }
    }

#pragma unroll
    for (int j = 0; j < NJ; ++j) {
        int col = bn + wn + j * 16 + fm;
        if (col >= N) continue;
        float badd = (b1 ? b1[col] : 0.f) + (b2 ? b2[col] : 0.f);
#pragma unroll
        for (int i = 0; i < MI; ++i) {
            int row0 = bm + wm + i * 16 + fq * 4;
            f32x4 v = acc[i][j];
#pragma unroll
            for (int rr = 0; rr < 4; ++rr)
                C[(size_t)(row0 + rr) * N + col] = v[rr] + badd;
        }
    }
}

// ---------------------------------------------------------------------------
// fp32 -> bf16 hi/lo plane split, 8 elems/thread
// ---------------------------------------------------------------------------
__global__ __launch_bounds__(256) void split_planes(
    const float* __restrict__ src, __bf16* __restrict__ hi,
    __bf16* __restrict__ lo, long n8)
{
    long i = (long)blockIdx.x * 256 + threadIdx.x;
    if (i >= n8) return;
    float4 a = ((const float4*)src)[2 * i];
    float4 b = ((const float4*)src)[2 * i + 1];
    float v[8] = {a.x, a.y, a.z, a.w, b.x, b.y, b.z, b.w};
    bf16x8 hh, ll;
#pragma unroll
    for (int j = 0; j < 8; ++j) {
        float x = v[j];
        __bf16 h = (__bf16)x;
        hh[j] = h;
        ll[j] = (__bf16)(x - (float)h);
    }
    ((bf16x8*)hi)[i] = hh;
    ((bf16x8*)lo)[i] = ll;
}

// ---------------------------------------------------------------------------
// LSTM pointwise; optionally emits h as bf16 hi/lo planes (free conversion)
// ---------------------------------------------------------------------------
__global__ __launch_bounds__(256) void lstm_pointwise(
    const float* __restrict__ gates, float* __restrict__ c, float* __restrict__ h,
    __bf16* __restrict__ hhi, __bf16* __restrict__ hlo)
{
    int i = blockIdx.x * blockDim.x + threadIdx.x;
    if (i >= B_ * H_) return;
    int b = i / H_, k = i % H_;
    const float* g = gates + (size_t)b * 4 * H_;
    float gi = g[k], gf = g[H_ + k], gg = g[2 * H_ + k], go = g[3 * H_ + k];
    float si = 1.f / (1.f + expf(-gi));
    float sf = 1.f / (1.f + expf(-gf));
    float so = 1.f / (1.f + expf(-go));
    float cn = sf * c[i] + si * tanhf(gg);
    c[i] = cn;
    float hv = so * tanhf(cn);
    h[i] = hv;
    if (hhi) {
        __bf16 hh = (__bf16)hv;
        hhi[i] = hh;
        hlo[i] = (__bf16)(hv - (float)hh);
    }
}

// ---------------------------------------------------------------------------
// Per-row argmax (first-occurrence) + online logsumexp. float4 loads (G13).
// ---------------------------------------------------------------------------
__global__ __launch_bounds__(256) void row_argmax_lse(
    const float* __restrict__ logits, int* __restrict__ tok,
    float* __restrict__ lp, int need_lp)
{
    int b = blockIdx.x;
    const float4* row4 = (const float4*)(logits + (size_t)b * V_);
    int tid = threadIdx.x;
    float m = -INFINITY; int mi = 0;
    float lm = -INFINITY, ls = 0.f;
    for (int j4 = tid; j4 < V_ / 4; j4 += 256) {
        float4 q = row4[j4];
        float vv[4] = {q.x, q.y, q.z, q.w};
#pragma unroll
        for (int u = 0; u < 4; ++u) {
            float v = vv[u];
            if (v > m) { m = v; mi = j4 * 4 + u; }
            if (need_lp) {
                if (v > lm) { ls = ls * expf(lm - v) + 1.f; lm = v; }
                else ls += expf(v - lm);
            }
        }
    }
    __shared__ float sm[256]; __shared__ int si[256];
    __shared__ float slm[256], sls[256];
    sm[tid] = m; si[tid] = mi; slm[tid] = lm; sls[tid] = ls;
    __syncthreads();
    for (int s = 128; s > 0; s >>= 1) {
        if (tid < s) {
            float vm = sm[tid + s]; int vi = si[tid + s];
            if (vm > sm[tid] || (vm == sm[tid] && vi < si[tid])) {
                sm[tid] = vm; si[tid] = vi;
            }
            if (need_lp) {
                float am = slm[tid], as = sls[tid];
                float bm2 = slm[tid + s], bs = sls[tid + s];
                if (am >= bm2) {
                    sls[tid] = as + bs * expf(bm2 - am);
                } else {
                    sls[tid] = bs + as * expf(am - bm2);
                    slm[tid] = bm2;
                }
            }
        }
        __syncthreads();
    }
    if (tid == 0) {
        tok[b] = si[0];
        if (need_lp) lp[b] = sm[0] - (slm[0] + logf(sls[0]));
    }
}

// ---------------------------------------------------------------------------
// Embedding gathers (fp32 versions for fallback; plane versions for fast path)
// ---------------------------------------------------------------------------
__global__ __launch_bounds__(128) void gather_emb(
    const float* __restrict__ emb, const int* __restrict__ tok,
    float* __restrict__ out)
{
    int b = blockIdx.x;
    int t = tok[b];
    const float4* src = (const float4*)(emb + (size_t)t * E_);
    float4* dst = (float4*)(out + (size_t)b * E_);
    for (int e = threadIdx.x; e < E_ / 4; e += blockDim.x) dst[e] = src[e];
}

__global__ __launch_bounds__(128) void broadcast_emb(
    const float* __restrict__ emb, const int* __restrict__ sidx,
    float* __restrict__ out)
{
    int b = blockIdx.x;
    int t = sidx[0];
    const float4* src = (const float4*)(emb + (size_t)t * E_);
    float4* dst = (float4*)(out + (size_t)b * E_);
    for (int e = threadIdx.x; e < E_ / 4; e += blockDim.x) dst[e] = src[e];
}

__device__ __forceinline__ void emb_row_split(
    const float* __restrict__ emb, int t, int b, int i,
    __bf16* __restrict__ whi, __bf16* __restrict__ wlo)
{
    const float4* src = (const float4*)(emb + (size_t)t * E_);
    float4 a = src[2 * i], c2 = src[2 * i + 1];
    float v[8] = {a.x, a.y, a.z, a.w, c2.x, c2.y, c2.z, c2.w};
    bf16x8 hh, ll;
#pragma unroll
    for (int j = 0; j < 8; ++j) {
        float x = v[j];
        __bf16 h = (__bf16)x;
        hh[j] = h;
        ll[j] = (__bf16)(x - (float)h);
    }
    ((bf16x8*)(whi + (size_t)b * E_))[i] = hh;
    ((bf16x8*)(wlo + (size_t)b * E_))[i] = ll;
}

__global__ __launch_bounds__(64) void gather_emb_planes(
    const float* __restrict__ emb, const int* __restrict__ tok,
    __bf16* __restrict__ whi, __bf16* __restrict__ wlo)
{
    emb_row_split(emb, tok[blockIdx.x], blockIdx.x, threadIdx.x, whi, wlo);
}

__global__ __launch_bounds__(64) void broadcast_emb_planes(
    const float* __restrict__ emb, const int* __restrict__ sidx,
    __bf16* __restrict__ whi, __bf16* __restrict__ wlo)
{
    emb_row_split(emb, sidx[0], blockIdx.x, threadIdx.x, whi, wlo);
}

__global__ __launch_bounds__(256) void zero_f32(float* __restrict__ p, int n)
{
    int i = blockIdx.x * blockDim.x + threadIdx.x;
    if (i < n) p[i] = 0.f;
}

// ---------------------------------------------------------------------------
// Loss rows + finalize (unchanged)
// ---------------------------------------------------------------------------
__global__ __launch_bounds__(256) void loss_rows(
    const float* __restrict__ sc, const float* __restrict__ lp,
    float* __restrict__ loss_part, float* __restrict__ acc_flag)
{
    int i = blockIdx.x; int tid = threadIdx.x;
    const float* tsrow = sc + (size_t)i * B_;
    float lsum = 0.f, tps = 0.f;
    float dps[4] = {0.f, 0.f, 0.f, 0.f};
    for (int j = tid; j < B_; j += 256) {
        float tsv = tsrow[j];
        float hv = 0.f;
#pragma unroll
        for (int d = 0; d < 4; ++d) {
            float dv = sc[((size_t)(1 + d) * B_ + i) * B_ + j];
            float t = 1.f - tsv + dv;
            hv += (t > 0.f) ? t : 0.f;
            dps[d] += expf(dv);
        }
        lsum += hv * lp[j];
        tps += expf(tsv);
    }
    __shared__ float red[6][256];
    red[0][tid] = lsum; red[1][tid] = tps;
    red[2][tid] = dps[0]; red[3][tid] = dps[1];
    red[4][tid] = dps[2]; red[5][tid] = dps[3];
    __syncthreads();
    for (int s = 128; s > 0; s >>= 1) {
        if (tid < s) {
#pragma unroll
            for (int q = 0; q < 6; ++q) red[q][tid] += red[q][tid + s];
        }
        __syncthreads();
    }
    if (tid == 0) {
        loss_part[i] = -red[0][0];
        float tp = red[1][0];
        float mx = fmaxf(fmaxf(red[2][0], red[3][0]), fmaxf(red[4][0], red[5][0]));
        acc_flag[i] = (tp >= mx) ? 1.f : 0.f;
    }
}

__global__ __launch_bounds__(256) void finalize_k(
    const float* __restrict__ loss_part, const float* __restrict__ acc_flag,
    float* __restrict__ out)
{
    int tid = threadIdx.x;
    float ls = 0.f, ac = 0.f;
    for (int i = tid; i < B_; i += 256) { ls += loss_part[i]; ac += acc_flag[i]; }
    __shared__ float s1[256], s2[256];
    s1[tid] = ls; s2[tid] = ac;
    __syncthreads();
    for (int s = 128; s > 0; s >>= 1) {
        if (tid < s) { s1[tid] += s1[tid + s]; s2[tid] += s2[tid + s]; }
        __syncthreads();
    }
    if (tid == 0) {
        out[0] = s1[0] / ((float)B_ * (float)B_);
        out[1] = s2[0] / (float)B_;
    }
}

// ---------------------------------------------------------------------------
// Host launcher
// ---------------------------------------------------------------------------
extern "C" void kernel_launch(void* const* d_in, const int* in_sizes, int n_in,
                              void* d_out, int out_size, void* d_ws, size_t ws_size,
                              hipStream_t stream)
{
    const float* target    = (const float*)d_in[0];
    const float* distract  = (const float*)d_in[1];
    const int*   start_tok = (const int*)d_in[2];
    const float* emb_s   = (const float*)d_in[4];
    const float* Wih_s   = (const float*)d_in[5];
    const float* Whh_s   = (const float*)d_in[6];
    const float* bih_s   = (const float*)d_in[7];
    const float* bhh_s   = (const float*)d_in[8];
    const float* aff_s_W = (const float*)d_in[9];
    const float* aff_s_b = (const float*)d_in[10];
    const float* probs_W = (const float*)d_in[11];
    const float* probs_b = (const float*)d_in[12];
    const float* emb_r   = (const float*)d_in[13];
    const float* Wih_r   = (const float*)d_in[14];
    const float* Whh_r   = (const float*)d_in[15];
    const float* bih_r   = (const float*)d_in[16];
    const float* bhh_r   = (const float*)d_in[17];
    const float* aff_r_W = (const float*)d_in[18];
    const float* aff_r_b = (const float*)d_in[19];

    float* ws = (float*)d_ws;
    // ---- base layout (identical to proven baseline)
    const size_t OFF_HS     = 0;
    const size_t OFF_CS     = 1048576;
    const size_t OFF_WE     = 2097152;
    const size_t OFF_GATES  = 2621440;
    const size_t OFF_HR     = 6815744;
    const size_t OFF_CR     = 7864320;
    const size_t OFF_LP     = 8912896;
    const size_t OFF_LOSSP  = 8916992;
    const size_t OFF_ACCF   = 8921088;
    const size_t OFF_MSG    = 8925184;
    const size_t OFF_LOGITS = 9437184;
    const size_t OFF_R      = 9437184;
    const size_t OFF_SC     = 13631488;
    // ---- bf16 plane region, LSTM loop (float offsets; plane = elems/2 floats)
    const size_t OFF_PROBS_HI = 29917184;  // [VPAD,H] bf16
    const size_t OFF_PROBS_LO = 40206336;
    const size_t OFF_WIHS_HI  = 50495488;  // [4H,E]
    const size_t OFF_WIHS_LO  = 51544064;
    const size_t OFF_WHHS_HI  = 52592640;  // [4H,H]
    const size_t OFF_WHHS_LO  = 54689792;
    const size_t OFF_WIHR_HI  = 56786944;
    const size_t OFF_WIHR_LO  = 57835520;
    const size_t OFF_WHHR_HI  = 58884096;
    const size_t OFF_WHHR_LO  = 60981248;
    const size_t OFF_WEP_HI   = 63078400;  // [B,E]
    const size_t OFF_WEP_LO   = 63340544;
    const size_t OFF_HSP_HI   = 63602688;  // [B,H]
    const size_t OFF_HSP_LO   = 64126976;
    const size_t OFF_HRP_HI   = 64651264;  // [B,H]
    const size_t OFF_HRP_LO   = 65175552;
    const size_t TOTAL_FLOATS = 65699840;  // 262.8 MB
    // ---- tail planes OVERLAY dead regions (no extra footprint):
    //   td  [5B,F] hi+lo (20.97M fl) -> probs/wihs region  (dead after sender)
    //   affr [F,H] hi+lo (4.19M fl)  -> wihr/whhr_hi       (dead after receiver)
    //   rp  [B,F] hi+lo  (4.19M fl)  -> gates              (dead at tail)
    const size_t OFF_TD_HI   = 29917184;   // ..40402944
    const size_t OFF_TD_LO   = 40402944;   // ..50888704 (< 56786944 OK)
    const size_t OFF_AFFR_HI = 56786944;   // ..58884096 (over wihr)
    const size_t OFF_AFFR_LO = 58884096;   // ..60981248 (over whhr_hi)
    const size_t OFF_RP_HI   = 2621440;    // ..4718592  (over gates)
    const size_t OFF_RP_LO   = 4718592;    // ..6815744

    float* h_s    = ws + OFF_HS;
    float* c_s    = ws + OFF_CS;
    float* w_e    = ws + OFF_WE;
    float* gates  = ws + OFF_GATES;
    float* h_r    = ws + OFF_HR;
    float* c_r    = ws + OFF_CR;
    float* lp     = ws + OFF_LP;
    float* lossp  = ws + OFF_LOSSP;
    float* accf   = ws + OFF_ACCF;
    int*   msg    = (int*)(ws + OFF_MSG);
    float* logits = ws + OFF_LOGITS;
    float* r_buf  = ws + OFF_R;
    float* sc     = ws + OFF_SC;

    auto gemm = [&](const float* A1, const float* W1, int K1,
                    const float* A2, const float* W2, int K2,
                    const float* b1, const float* b2,
                    float* C, int M, int N) {
        dim3 grid((N + BN - 1) / BN, M / BM);
        gemm_nt_split<<<grid, dim3(256), 0, stream>>>(A1, W1, K1, A2, W2, K2,
                                                      b1, b2, C, M, N);
    };

    const bool fast = ws_size >= TOTAL_FLOATS * sizeof(float);

    if (fast) {
        __bf16* probs_hi = (__bf16*)(ws + OFF_PROBS_HI);
        __bf16* probs_lo = (__bf16*)(ws + OFF_PROBS_LO);
        __bf16* wihs_hi  = (__bf16*)(ws + OFF_WIHS_HI);
        __bf16* wihs_lo  = (__bf16*)(ws + OFF_WIHS_LO);
        __bf16* whhs_hi  = (__bf16*)(ws + OFF_WHHS_HI);
        __bf16* whhs_lo  = (__bf16*)(ws + OFF_WHHS_LO);
        __bf16* wihr_hi  = (__bf16*)(ws + OFF_WIHR_HI);
        __bf16* wihr_lo  = (__bf16*)(ws + OFF_WIHR_LO);
        __bf16* whhr_hi  = (__bf16*)(ws + OFF_WHHR_HI);
        __bf16* whhr_lo  = (__bf16*)(ws + OFF_WHHR_LO);
        __bf16* we_hi    = (__bf16*)(ws + OFF_WEP_HI);
        __bf16* we_lo    = (__bf16*)(ws + OFF_WEP_LO);
        __bf16* hs_hi    = (__bf16*)(ws + OFF_HSP_HI);
        __bf16* hs_lo    = (__bf16*)(ws + OFF_HSP_LO);
        __bf16* hr_hi    = (__bf16*)(ws + OFF_HRP_HI);
        __bf16* hr_lo    = (__bf16*)(ws + OFF_HRP_LO);
        __bf16* td_hi    = (__bf16*)(ws + OFF_TD_HI);
        __bf16* td_lo    = (__bf16*)(ws + OFF_TD_LO);
        __bf16* affr_hi  = (__bf16*)(ws + OFF_AFFR_HI);
        __bf16* affr_lo  = (__bf16*)(ws + OFF_AFFR_LO);
        __bf16* rp_hi    = (__bf16*)(ws + OFF_RP_HI);
        __bf16* rp_lo    = (__bf16*)(ws + OFF_RP_LO);

        auto cvt = [&](const float* src, __bf16* hi, __bf16* lo, long n) {
            long n8 = n / 8;
            split_planes<<<(unsigned)((n8 + 255) / 256), 256, 0, stream>>>(
                src, hi, lo, n8);
        };
        auto gemmP = [&](const __bf16* Ah1, const __bf16* Al1,
                         const __bf16* Wh1, const __bf16* Wl1, int K1,
                         const __bf16* Ah2, const __bf16* Al2,
                         const __bf16* Wh2, const __bf16* Wl2, int K2,
                         const float* b1, const float* b2,
                         float* C, int M, int N) {
            dim3 grid((N + BN - 1) / BN, M / BM);
            gemm_nt_planes_t<128, 128><<<grid, dim3(256), 0, stream>>>(
                Ah1, Al1, Wh1, Wl1, K1, Ah2, Al2, Wh2, Wl2, K2, b1, b2, C, M, N);
        };
        auto gemmP64 = [&](const __bf16* Ah1, const __bf16* Al1,
                           const __bf16* Wh1, const __bf16* Wl1, int K1,
                           const __bf16* Ah2, const __bf16* Al2,
                           const __bf16* Wh2, const __bf16* Wl2, int K2,
                           const float* b1, const float* b2,
                           float* C, int M, int N) {
            dim3 grid((N + 63) / 64, M / BM);
            gemm_nt_planes_t<128, 64><<<grid, dim3(256), 0, stream>>>(
                Ah1, Al1, Wh1, Wl1, K1, Ah2, Al2, Wh2, Wl2, K2, b1, b2, C, M, N);
        };

        // ---- per-launch weight plane conversions (sender+receiver weights;
        //      these regions are re-converted each launch because the tail
        //      overlays them with td/affr planes)
        cvt(probs_W, probs_hi, probs_lo, (long)V_ * H_);
        cvt(Wih_s, wihs_hi, wihs_lo, (long)4 * H_ * E_);
        cvt(Whh_s, whhs_hi, whhs_lo, (long)4 * H_ * H_);
        cvt(Wih_r, wihr_hi, wihr_lo, (long)4 * H_ * E_);
        cvt(Whh_r, whhr_hi, whhr_lo, (long)4 * H_ * H_);
        // zero probs pad rows (20000..20095) for determinism
        {
            int padn = (VPAD - V_) * H_ / 2;  // floats
            zero_f32<<<(padn + 255) / 256, 256, 0, stream>>>(
                ws + OFF_PROBS_HI + (size_t)V_ * H_ / 2, padn);
            zero_f32<<<(padn + 255) / 256, 256, 0, stream>>>(
                ws + OFF_PROBS_LO + (size_t)V_ * H_ / 2, padn);
        }

        // ---- Sender ----
        gemm(target, aff_s_W, F_, nullptr, nullptr, 0, aff_s_b, nullptr,
             h_s, B_, H_);
        cvt(h_s, hs_hi, hs_lo, (long)B_ * H_);
        zero_f32<<<(B_ * H_ + 255) / 256, 256, 0, stream>>>(c_s, B_ * H_);
        broadcast_emb_planes<<<B_, 64, 0, stream>>>(emb_s, start_tok, we_hi, we_lo);

        for (int t = 0; t < L_; ++t) {
            gemmP64(we_hi, we_lo, wihs_hi, wihs_lo, E_,
                    hs_hi, hs_lo, whhs_hi, whhs_lo, H_,
                    bih_s, bhh_s, gates, B_, 4 * H_);
            lstm_pointwise<<<(B_ * H_ + 255) / 256, 256, 0, stream>>>(
                gates, c_s, h_s, hs_hi, hs_lo);
            gemmP(hs_hi, hs_lo, probs_hi, probs_lo, H_,
                  nullptr, nullptr, nullptr, nullptr, 0,
                  probs_b, nullptr, logits, B_, V_);
            row_argmax_lse<<<B_, 256, 0, stream>>>(logits, msg + (size_t)t * B_, lp,
                                                   (t == L_ - 1) ? 1 : 0);
            if (t < L_ - 1)
                gather_emb_planes<<<B_, 64, 0, stream>>>(emb_s, msg + (size_t)t * B_,
                                                         we_hi, we_lo);
        }

        // ---- Receiver ----
        zero_f32<<<(B_ * H_ + 255) / 256, 256, 0, stream>>>(h_r, B_ * H_);
        zero_f32<<<(B_ * H_ + 255) / 256, 256, 0, stream>>>(c_r, B_ * H_);
        zero_f32<<<(B_ * H_ / 2 + 255) / 256, 256, 0, stream>>>(
            ws + OFF_HRP_HI, B_ * H_ / 2);
        zero_f32<<<(B_ * H_ / 2 + 255) / 256, 256, 0, stream>>>(
            ws + OFF_HRP_LO, B_ * H_ / 2);
        for (int t = 0; t < L_; ++t) {
            gather_emb_planes<<<B_, 64, 0, stream>>>(emb_r, msg + (size_t)t * B_,
                                                     we_hi, we_lo);
            gemmP64(we_hi, we_lo, wihr_hi, wihr_lo, E_,
                    hr_hi, hr_lo, whhr_hi, whhr_lo, H_,
                    bih_r, bhh_r, gates, B_, 4 * H_);
            lstm_pointwise<<<(B_ * H_ + 255) / 256, 256, 0, stream>>>(
                gates, c_r, h_r, hr_hi, hr_lo);
        }

        // ---- tail (all planes; overlays now safe: sender/receiver done) ----
        cvt(aff_r_W, affr_hi, affr_lo, (long)F_ * H_);
        // r = h_r @ aff_r_W.T + b   (512 blocks)
        gemmP64(hr_hi, hr_lo, affr_hi, affr_lo, H_,
                nullptr, nullptr, nullptr, nullptr, 0,
                aff_r_b, nullptr, r_buf, B_, F_);
        cvt(r_buf, rp_hi, rp_lo, (long)B_ * F_);
        cvt(target, td_hi, td_lo, (long)B_ * F_);
        cvt(distract, td_hi + (size_t)B_ * F_, td_lo + (size_t)B_ * F_,
            (long)D_ * B_ * F_);
        // fused [target; distract] @ r.T -> sc [5B, B]   (640 blocks)
        gemmP64(td_hi, td_lo, rp_hi, rp_lo, F_,
                nullptr, nullptr, nullptr, nullptr, 0,
                nullptr, nullptr, sc, (1 + D_) * B_, B_);
    } else {
        // ---- fallback: proven fp32-split path (ws too small for planes)
        gemm(target, aff_s_W, F_, nullptr, nullptr, 0, aff_s_b, nullptr, h_s, B_, H_);
        zero_f32<<<(B_ * H_ + 255) / 256, 256, 0, stream>>>(c_s, B_ * H_);
        broadcast_emb<<<B_, 128, 0, stream>>>(emb_s, start_tok, w_e);

        for (int t = 0; t < L_; ++t) {
            gemm(w_e, Wih_s, E_, h_s, Whh_s, H_, bih_s, bhh_s, gates, B_, 4 * H_);
            lstm_pointwise<<<(B_ * H_ + 255) / 256, 256, 0, stream>>>(
                gates, c_s, h_s, nullptr, nullptr);
            gemm(h_s, probs_W, H_, nullptr, nullptr, 0, probs_b, nullptr,
                 logits, B_, V_);
            row_argmax_lse<<<B_, 256, 0, stream>>>(logits, msg + (size_t)t * B_, lp,
                                                   (t == L_ - 1) ? 1 : 0);
            if (t < L_ - 1)
                gather_emb<<<B_, 128, 0, stream>>>(emb_s, msg + (size_t)t * B_, w_e);
        }

        zero_f32<<<(B_ * H_ + 255) / 256, 256, 0, stream>>>(h_r, B_ * H_);
        zero_f32<<<(B_ * H_ + 255) / 256, 256, 0, stream>>>(c_r, B_ * H_);
        for (int t = 0; t < L_; ++t) {
            gather_emb<<<B_, 128, 0, stream>>>(emb_r, msg + (size_t)t * B_, w_e);
            gemm(w_e, Wih_r, E_, h_r, Whh_r, H_, bih_r, bhh_r, gates, B_, 4 * H_);
            lstm_pointwise<<<(B_ * H_ + 255) / 256, 256, 0, stream>>>(
                gates, c_r, h_r, nullptr, nullptr);
        }

        gemm(h_r, aff_r_W, H_, nullptr, nullptr, 0, aff_r_b, nullptr, r_buf, B_, F_);
        gemm(target, r_buf, F_, nullptr, nullptr, 0, nullptr, nullptr, sc, B_, B_);
        gemm(distract, r_buf, F_, nullptr, nullptr, 0, nullptr, nullptr,
             sc + (size_t)B_ * B_, D_ * B_, B_);
    }

    // ---- loss + accuracy (common) ----
    loss_rows<<<B_, 256, 0, stream>>>(sc, lp, lossp, accf);
    finalize_k<<<1, 256, 0, stream>>>(lossp, accf, (float*)d_out);
}